// Round 6
// baseline (246.964 us; speedup 1.0000x reference)
//
#include <hip/hip_runtime.h>

#define N_TOK 4096
#define BATCH 4

typedef __attribute__((ext_vector_type(8))) short short8;
typedef __attribute__((ext_vector_type(4))) float floatx4;

__device__ __forceinline__ unsigned short bf16_rne(float x) {
    union { float f; unsigned u; } v; v.f = x;
    unsigned r = v.u + 0x7fffu + ((v.u >> 16) & 1u);
    return (unsigned short)(r >> 16);
}
__device__ __forceinline__ float bf16_f32(unsigned short h) {
    union { unsigned u; float f; } v; v.u = ((unsigned)h) << 16;
    return v.f;
}
__device__ __forceinline__ unsigned pack_bf16_pair(float a, float b) {
    return (unsigned)bf16_rne(a) | ((unsigned)bf16_rne(b) << 16);
}

// Full-rate exp2: round-to-int via magic add, deg-3 Taylor on f in [-0.5,0.5],
// exponent injected by integer add.  Rel err ~6e-4 << bf16 rounding (2e-3).
// Replaces v_exp_f32 which measures ~1/16 rate on gfx950 (R5 census).
__device__ __forceinline__ float exp2_fast(float x) {
    const float MAGIC = 12582912.0f;            // 1.5 * 2^23
    float tm = x + MAGIC;
    float f  = x - (tm - MAGIC);
    float p  = fmaf(f, fmaf(f, fmaf(f, 0.0555041f, 0.2402265f), 0.6931472f), 1.0f);
    unsigned e = __float_as_uint(tm) << 23;
    return __uint_as_float(__float_as_uint(p) + e);
}

// ---------------------------------------------------------------------------
// Convert weights to bf16 hi/lo (layout preserved).  w_qkv: 384x256,
// w_out: 256x128.  Grid 128 x 256 thr, 4 floats/thread.
// ---------------------------------------------------------------------------
__global__ __launch_bounds__(256) void convert_w(
    const float* __restrict__ wq, const float* __restrict__ wo,
    unsigned short* __restrict__ Wqh, unsigned short* __restrict__ Wql,
    unsigned short* __restrict__ Woh, unsigned short* __restrict__ Wol)
{
    const int idx = blockIdx.x * 256 + threadIdx.x;   // group of 4 floats
    const float* src; unsigned short *dh, *dl; int off;
    if (idx < 24576) { src = wq; dh = Wqh; dl = Wql; off = idx * 4; }
    else             { src = wo; dh = Woh; dl = Wol; off = (idx - 24576) * 4; }
    float4 v = *(const float4*)(src + off);
    float xs[4] = {v.x, v.y, v.z, v.w};
    unsigned short hh[4]; float rem[4];
#pragma unroll
    for (int e = 0; e < 4; ++e) {
        hh[e] = bf16_rne(xs[e]);
        rem[e] = xs[e] - bf16_f32(hh[e]);
    }
    uint2 ph, pl;
    ph.x = (unsigned)hh[0] | ((unsigned)hh[1] << 16);
    ph.y = (unsigned)hh[2] | ((unsigned)hh[3] << 16);
    pl.x = pack_bf16_pair(rem[0], rem[1]);
    pl.y = pack_bf16_pair(rem[2], rem[3]);
    *(uint2*)(dh + off) = ph;
    *(uint2*)(dl + off) = pl;
}

// ---------------------------------------------------------------------------
// Convert+transpose x: fp32 [b][k=256][n] -> bf16 hi/lo [b][n][k].
// 64k x 64n tiles through LDS.  Grid (64 n-tiles, 4 k-tiles, 4 b).
// ---------------------------------------------------------------------------
__global__ __launch_bounds__(256) void convert_x(
    const float* __restrict__ x,
    unsigned short* __restrict__ Xth, unsigned short* __restrict__ Xtl)
{
    const int N = N_TOK;
    const int b = blockIdx.z;
    const int k0 = blockIdx.y * 64;
    const int n0 = blockIdx.x * 64;
    const int t = threadIdx.x;

    __shared__ float Lx[64][68];   // [k][n]; stride 68: b128-aligned rows, 2-way max on strided read

    {
        const int kr = t >> 2, nb = (t & 3) * 16;
        const float* src = x + ((size_t)b * 256 + k0 + kr) * N + n0 + nb;
#pragma unroll
        for (int j = 0; j < 4; ++j)
            *(float4*)&Lx[kr][nb + j * 4] = *(const float4*)(src + j * 4);
    }
    __syncthreads();
    {
        const int nr = t >> 2, kb = (t & 3) * 16;
        float v[16];
#pragma unroll
        for (int i = 0; i < 16; ++i) v[i] = Lx[kb + i][nr];
        unsigned ph[8], pl[8];
#pragma unroll
        for (int q = 0; q < 8; ++q) {
            unsigned short h0 = bf16_rne(v[2 * q]);
            unsigned short h1 = bf16_rne(v[2 * q + 1]);
            float r0 = v[2 * q] - bf16_f32(h0);
            float r1 = v[2 * q + 1] - bf16_f32(h1);
            ph[q] = (unsigned)h0 | ((unsigned)h1 << 16);
            pl[q] = pack_bf16_pair(r0, r1);
        }
        unsigned short* dh = Xth + ((size_t)b * N + n0 + nr) * 256 + k0 + kb;
        unsigned short* dl = Xtl + ((size_t)b * N + n0 + nr) * 256 + k0 + kb;
        *(uint4*)&dh[0] = *(uint4*)&ph[0];
        *(uint4*)&dh[8] = *(uint4*)&ph[4];
        *(uint4*)&dl[0] = *(uint4*)&pl[0];
        *(uint4*)&dl[8] = *(uint4*)&pl[4];
    }
}

// ---------------------------------------------------------------------------
// QKV GEMM, split-bf16 MFMA (3-term: WhXh + WhXl + WlXh, rel err ~2^-18).
// A-frags from Wq hi/lo [m][k] global; B-frags from Xt hi/lo [n][k] global.
// No operand LDS.  Fused pack epilogue (layouts identical to R5):
//   region 0 (Q): Qp[bh][n][d] bf16 * (1/sqrt(32))*log2(e)
//   region 1 (K): Kp[bh][n][d] bf16
//   region 2 (V): Vp[b*128+ch][n] bf16
// Grid (64 n, 6 m, 4 b); 4 waves, each 32m x 32n.
// ---------------------------------------------------------------------------
__global__ __launch_bounds__(256) void gemm1_mfma(
    const unsigned short* __restrict__ Wqh, const unsigned short* __restrict__ Wql,
    const unsigned short* __restrict__ Xth, const unsigned short* __restrict__ Xtl,
    unsigned short* __restrict__ Qp, unsigned short* __restrict__ Kp,
    unsigned short* __restrict__ Vp)
{
    const int N = N_TOK;
    const int b = blockIdx.z;
    const int row0 = blockIdx.y * 64;
    const int col0 = blockIdx.x * 64;
    const int t = threadIdx.x;
    const int wave = t >> 6, lane = t & 63;
    const int l16 = lane & 15, quad = lane >> 4;
    const int msub0 = (wave & 1) * 32, nsub0 = (wave >> 1) * 32;

    __shared__ unsigned short LdsT[64][68];   // [n][m] bf16 (Q/K transpose)
    __shared__ float LdsF[64][68];            // [m][n] fp32 (V)

    const unsigned short* aH = Wqh + (size_t)(row0 + msub0 + l16) * 256 + quad * 8;
    const unsigned short* aL = Wql + (size_t)(row0 + msub0 + l16) * 256 + quad * 8;
    const unsigned short* bH = Xth + ((size_t)b * N + col0 + nsub0 + l16) * 256 + quad * 8;
    const unsigned short* bL = Xtl + ((size_t)b * N + col0 + nsub0 + l16) * 256 + quad * 8;

    floatx4 acc[2][2] = {};
#pragma unroll
    for (int ks = 0; ks < 8; ++ks) {
        short8 ah0 = *(const short8*)(aH + ks * 32);
        short8 ah1 = *(const short8*)(aH + 16 * 256 + ks * 32);
        short8 al0 = *(const short8*)(aL + ks * 32);
        short8 al1 = *(const short8*)(aL + 16 * 256 + ks * 32);
        short8 bh0 = *(const short8*)(bH + ks * 32);
        short8 bh1 = *(const short8*)(bH + 16 * 256 + ks * 32);
        short8 bl0 = *(const short8*)(bL + ks * 32);
        short8 bl1 = *(const short8*)(bL + 16 * 256 + ks * 32);
        acc[0][0] = __builtin_amdgcn_mfma_f32_16x16x32_bf16(ah0, bh0, acc[0][0], 0, 0, 0);
        acc[0][1] = __builtin_amdgcn_mfma_f32_16x16x32_bf16(ah0, bh1, acc[0][1], 0, 0, 0);
        acc[1][0] = __builtin_amdgcn_mfma_f32_16x16x32_bf16(ah1, bh0, acc[1][0], 0, 0, 0);
        acc[1][1] = __builtin_amdgcn_mfma_f32_16x16x32_bf16(ah1, bh1, acc[1][1], 0, 0, 0);
        acc[0][0] = __builtin_amdgcn_mfma_f32_16x16x32_bf16(ah0, bl0, acc[0][0], 0, 0, 0);
        acc[0][1] = __builtin_amdgcn_mfma_f32_16x16x32_bf16(ah0, bl1, acc[0][1], 0, 0, 0);
        acc[1][0] = __builtin_amdgcn_mfma_f32_16x16x32_bf16(ah1, bl0, acc[1][0], 0, 0, 0);
        acc[1][1] = __builtin_amdgcn_mfma_f32_16x16x32_bf16(ah1, bl1, acc[1][1], 0, 0, 0);
        acc[0][0] = __builtin_amdgcn_mfma_f32_16x16x32_bf16(al0, bh0, acc[0][0], 0, 0, 0);
        acc[0][1] = __builtin_amdgcn_mfma_f32_16x16x32_bf16(al0, bh1, acc[0][1], 0, 0, 0);
        acc[1][0] = __builtin_amdgcn_mfma_f32_16x16x32_bf16(al1, bh0, acc[1][0], 0, 0, 0);
        acc[1][1] = __builtin_amdgcn_mfma_f32_16x16x32_bf16(al1, bh1, acc[1][1], 0, 0, 0);
    }

    const int region = row0 >> 7;   // 0=Q, 1=K, 2=V
    if (region == 2) {
#pragma unroll
        for (int i = 0; i < 2; ++i)
#pragma unroll
            for (int j = 0; j < 2; ++j) {
                const int m = msub0 + i * 16 + quad * 4;
                const int n = nsub0 + j * 16 + l16;
#pragma unroll
                for (int r = 0; r < 4; ++r) LdsF[m + r][n] = acc[i][j][r];
            }
        __syncthreads();
        const int m = t >> 2, nb = (t & 3) * 16;
        const int vrow = b * 128 + (row0 - 256) + m;
        unsigned pk[8];
#pragma unroll
        for (int q = 0; q < 8; ++q)
            pk[q] = pack_bf16_pair(LdsF[m][nb + 2 * q], LdsF[m][nb + 2 * q + 1]);
        unsigned short* dst = Vp + (size_t)vrow * N + col0 + nb;
        *(uint4*)&dst[0] = *(uint4*)&pk[0];
        *(uint4*)&dst[8] = *(uint4*)&pk[4];
    } else {
        const float sc = region ? 1.0f
                                : (0.17677669529663687f * 1.4426950408889634f);
#pragma unroll
        for (int i = 0; i < 2; ++i)
#pragma unroll
            for (int j = 0; j < 2; ++j) {
                const int m = msub0 + i * 16 + quad * 4;
                const int n = nsub0 + j * 16 + l16;
                uint2 pr;
                pr.x = pack_bf16_pair(acc[i][j][0] * sc, acc[i][j][1] * sc);
                pr.y = pack_bf16_pair(acc[i][j][2] * sc, acc[i][j][3] * sc);
                *(uint2*)&LdsT[n][m] = pr;
            }
        __syncthreads();
        const int n = t & 63, hb = (t >> 6) & 1, dh = t >> 7;
        const int h = ((row0 & 127) >> 5) + hb;
        const int m0 = hb * 32 + dh * 16;
        unsigned tmp[8];
        *(uint2*)&tmp[0] = *(const uint2*)&LdsT[n][m0];
        *(uint2*)&tmp[2] = *(const uint2*)&LdsT[n][m0 + 4];
        *(uint2*)&tmp[4] = *(const uint2*)&LdsT[n][m0 + 8];
        *(uint2*)&tmp[6] = *(const uint2*)&LdsT[n][m0 + 12];
        unsigned short* dst = (region ? Kp : Qp) +
            ((size_t)(b * 4 + h) * N + col0 + n) * 32 + dh * 16;
        *(uint4*)&dst[0] = *(uint4*)&tmp[0];
        *(uint4*)&dst[8] = *(uint4*)&tmp[4];
    }
}

// ---------------------------------------------------------------------------
// MFMA flash attention (as R5) with full-rate poly exp2 and uint2 P stores.
// Key-split 4-way; Opart segs 0,1 -> OpA buffer, segs 2,3 -> OpB.
// ---------------------------------------------------------------------------
__global__ __launch_bounds__(256) void attn_mfma(
    const unsigned short* __restrict__ QpH,
    const unsigned short* __restrict__ KpH,
    const unsigned short* __restrict__ VpH,
    float* __restrict__ OpA, float* __restrict__ OpB,
    float* __restrict__ Lpart)
{
    const int N = N_TOK;
    const int bh = blockIdx.z;
    const int seg = blockIdx.y;
    const int i0 = blockIdx.x * 128;
    const int j0 = seg * 1024;
    const int t = threadIdx.x;
    const int wave = t >> 6, lane = t & 63;
    const int l16 = lane & 15, quad = lane >> 4;

    __shared__ unsigned short KsH[64][40];     // [key][d]
    __shared__ unsigned short VsH[32][72];     // [d][key]
    __shared__ unsigned short Pt[4][32][72];   // per-wave [q][key]

    short8 ones;
#pragma unroll
    for (int e = 0; e < 8; ++e) ones[e] = (short)0x3F80;   // bf16 1.0

    short8 qh[2];
#pragma unroll
    for (int g = 0; g < 2; ++g)
        qh[g] = *(const short8*)(QpH +
            ((size_t)bh * N + i0 + wave * 32 + g * 16 + l16) * 32 + quad * 8);

    floatx4 o[2][2] = {};
    floatx4 lacc[2] = {};

    const int skey = t >> 2, sdp = (t & 3) * 8;
    const unsigned short* kp = KpH + ((size_t)bh * N + j0 + skey) * 32 + sdp;
    const int svd = t >> 3, svp = (t & 7) * 8;
    const unsigned short* vp = VpH + ((size_t)bh * 32 + svd) * N + j0 + svp;

    short8 kreg = *(const short8*)kp;
    short8 vreg = *(const short8*)vp;

    for (int it = 0; it < 16; ++it) {
        __syncthreads();
        *(short8*)&KsH[skey][sdp] = kreg;
        *(short8*)&VsH[svd][svp] = vreg;
        __syncthreads();

        if (it + 1 < 16) {
            kp += 64 * 32; vp += 64;
            kreg = *(const short8*)kp;
            vreg = *(const short8*)vp;
        }

        short8 kh0 = *(const short8*)&KsH[ 0 + l16][quad * 8];
        short8 kh1 = *(const short8*)&KsH[16 + l16][quad * 8];
        short8 kh2 = *(const short8*)&KsH[32 + l16][quad * 8];
        short8 kh3 = *(const short8*)&KsH[48 + l16][quad * 8];

#pragma unroll
        for (int g = 0; g < 2; ++g) {
            const floatx4 z = {0.0f, 0.0f, 0.0f, 0.0f};
            floatx4 st[4];
            st[0] = __builtin_amdgcn_mfma_f32_16x16x32_bf16(kh0, qh[g], z, 0, 0, 0);
            st[1] = __builtin_amdgcn_mfma_f32_16x16x32_bf16(kh1, qh[g], z, 0, 0, 0);
            st[2] = __builtin_amdgcn_mfma_f32_16x16x32_bf16(kh2, qh[g], z, 0, 0, 0);
            st[3] = __builtin_amdgcn_mfma_f32_16x16x32_bf16(kh3, qh[g], z, 0, 0, 0);

#pragma unroll
            for (int s = 0; s < 4; ++s) {
                float p0 = exp2_fast(st[s][0]);
                float p1 = exp2_fast(st[s][1]);
                float p2 = exp2_fast(st[s][2]);
                float p3 = exp2_fast(st[s][3]);
                uint2 pr;
                pr.x = pack_bf16_pair(p0, p1);
                pr.y = pack_bf16_pair(p2, p3);
                *(uint2*)&Pt[wave][g * 16 + l16][s * 16 + quad * 4] = pr;
            }
        }

#pragma unroll
        for (int ks = 0; ks < 2; ++ks) {
            short8 pf0 = *(const short8*)&Pt[wave][ 0 + l16][ks * 32 + quad * 8];
            short8 pf1 = *(const short8*)&Pt[wave][16 + l16][ks * 32 + quad * 8];
            short8 vh0 = *(const short8*)&VsH[ 0 + l16][ks * 32 + quad * 8];
            short8 vh1 = *(const short8*)&VsH[16 + l16][ks * 32 + quad * 8];
            o[0][0] = __builtin_amdgcn_mfma_f32_16x16x32_bf16(vh0, pf0, o[0][0], 0, 0, 0);
            o[0][1] = __builtin_amdgcn_mfma_f32_16x16x32_bf16(vh1, pf0, o[0][1], 0, 0, 0);
            o[1][0] = __builtin_amdgcn_mfma_f32_16x16x32_bf16(vh0, pf1, o[1][0], 0, 0, 0);
            o[1][1] = __builtin_amdgcn_mfma_f32_16x16x32_bf16(vh1, pf1, o[1][1], 0, 0, 0);
            lacc[0] = __builtin_amdgcn_mfma_f32_16x16x32_bf16(ones, pf0, lacc[0], 0, 0, 0);
            lacc[1] = __builtin_amdgcn_mfma_f32_16x16x32_bf16(ones, pf1, lacc[1], 0, 0, 0);
        }
    }

    float* OP = (seg < 2) ? OpA : OpB;
    const int segl = seg & 1;
#pragma unroll
    for (int g = 0; g < 2; ++g) {
        const int n = i0 + wave * 32 + g * 16 + l16;
#pragma unroll
        for (int half = 0; half < 2; ++half)
#pragma unroll
            for (int r = 0; r < 4; ++r) {
                const int d = half * 16 + quad * 4 + r;
                OP[((size_t)segl * 512 + bh * 32 + d) * N + n] = o[g][half][r];
            }
        Lpart[((size_t)seg * 16 + bh) * N + n] = lacc[g][0];
    }
}

// ---------------------------------------------------------------------------
// Combine 4 key-segments, normalize, transpose to Ot[b][n][c=128] bf16 hi/lo
// (the gemm2 B-operand layout).  Grid (64 n-tiles, 4 b).
// ---------------------------------------------------------------------------
__global__ __launch_bounds__(256) void combine_kernel(
    const float* __restrict__ OpA, const float* __restrict__ OpB,
    const float* __restrict__ Lpart,
    unsigned short* __restrict__ Oth, unsigned short* __restrict__ Otl)
{
    const int N = N_TOK;
    const int b = blockIdx.y;
    const int n0 = blockIdx.x * 64;
    const int t = threadIdx.x;

    __shared__ float Ls[128][68];   // [c][n] normalized fp32

    {
        const int c = t >> 1, nh = (t & 1) * 32;
        const int h = c >> 5;
        float acc[32], lsum[32];
#pragma unroll
        for (int i = 0; i < 32; i += 4) {
            *(float4*)&acc[i] = *(const float4*)&OpA[((size_t)(b * 128 + c)) * N + n0 + nh + i];
            *(float4*)&lsum[i] = *(const float4*)&Lpart[((size_t)(b * 4 + h)) * N + n0 + nh + i];
        }
#pragma unroll
        for (int s = 1; s < 4; ++s) {
            const float* base = (s < 2) ? OpA : OpB;
            const size_t row = (size_t)(s & 1) * 512 + b * 128 + c;
            const size_t lrow = (size_t)s * 16 + b * 4 + h;
#pragma unroll
            for (int i = 0; i < 32; i += 4) {
                float4 o4 = *(const float4*)&base[row * N + n0 + nh + i];
                float4 l4 = *(const float4*)&Lpart[lrow * N + n0 + nh + i];
                acc[i] += o4.x; acc[i+1] += o4.y; acc[i+2] += o4.z; acc[i+3] += o4.w;
                lsum[i] += l4.x; lsum[i+1] += l4.y; lsum[i+2] += l4.z; lsum[i+3] += l4.w;
            }
        }
#pragma unroll
        for (int i = 0; i < 32; ++i) Ls[c][nh + i] = acc[i] / lsum[i];
    }
    __syncthreads();
#pragma unroll
    for (int u = 0; u < 2; ++u) {
        const int idx = t * 2 + u;
        const int n = idx >> 3, cc = (idx & 7) * 16;
        unsigned ph[8], pl[8];
#pragma unroll
        for (int q = 0; q < 8; ++q) {
            float v0 = Ls[cc + 2 * q][n], v1 = Ls[cc + 2 * q + 1][n];
            unsigned short h0 = bf16_rne(v0); float r0 = v0 - bf16_f32(h0);
            unsigned short h1 = bf16_rne(v1); float r1 = v1 - bf16_f32(h1);
            ph[q] = (unsigned)h0 | ((unsigned)h1 << 16);
            pl[q] = pack_bf16_pair(r0, r1);
        }
        unsigned short* dh = Oth + ((size_t)b * N + n0 + n) * 128 + cc;
        unsigned short* dl = Otl + ((size_t)b * N + n0 + n) * 128 + cc;
        *(uint4*)&dh[0] = *(uint4*)&ph[0];
        *(uint4*)&dh[8] = *(uint4*)&ph[4];
        *(uint4*)&dl[0] = *(uint4*)&pl[0];
        *(uint4*)&dl[8] = *(uint4*)&pl[4];
    }
}

// ---------------------------------------------------------------------------
// Output GEMM, split-bf16 MFMA (3-term), + bias.  A = w_out hi/lo [m][128],
// B = Ot hi/lo [n][128], both direct-from-global frags.  Grid (64 n, 4 m, 4 b).
// ---------------------------------------------------------------------------
__global__ __launch_bounds__(256) void gemm2_mfma(
    const unsigned short* __restrict__ Woh, const unsigned short* __restrict__ Wol,
    const unsigned short* __restrict__ Oth, const unsigned short* __restrict__ Otl,
    const float* __restrict__ bias, float* __restrict__ y)
{
    const int N = N_TOK;
    const int b = blockIdx.z;
    const int row0 = blockIdx.y * 64;
    const int col0 = blockIdx.x * 64;
    const int t = threadIdx.x;
    const int wave = t >> 6, lane = t & 63;
    const int l16 = lane & 15, quad = lane >> 4;
    const int msub0 = (wave & 1) * 32, nsub0 = (wave >> 1) * 32;

    __shared__ float LdsF[64][68];   // [m][n]

    const unsigned short* aH = Woh + (size_t)(row0 + msub0 + l16) * 128 + quad * 8;
    const unsigned short* aL = Wol + (size_t)(row0 + msub0 + l16) * 128 + quad * 8;
    const unsigned short* bH = Oth + ((size_t)b * N + col0 + nsub0 + l16) * 128 + quad * 8;
    const unsigned short* bL = Otl + ((size_t)b * N + col0 + nsub0 + l16) * 128 + quad * 8;

    floatx4 acc[2][2] = {};
#pragma unroll
    for (int ks = 0; ks < 4; ++ks) {
        short8 ah0 = *(const short8*)(aH + ks * 32);
        short8 ah1 = *(const short8*)(aH + 16 * 128 + ks * 32);
        short8 al0 = *(const short8*)(aL + ks * 32);
        short8 al1 = *(const short8*)(aL + 16 * 128 + ks * 32);
        short8 bh0 = *(const short8*)(bH + ks * 32);
        short8 bh1 = *(const short8*)(bH + 16 * 128 + ks * 32);
        short8 bl0 = *(const short8*)(bL + ks * 32);
        short8 bl1 = *(const short8*)(bL + 16 * 128 + ks * 32);
        acc[0][0] = __builtin_amdgcn_mfma_f32_16x16x32_bf16(ah0, bh0, acc[0][0], 0, 0, 0);
        acc[0][1] = __builtin_amdgcn_mfma_f32_16x16x32_bf16(ah0, bh1, acc[0][1], 0, 0, 0);
        acc[1][0] = __builtin_amdgcn_mfma_f32_16x16x32_bf16(ah1, bh0, acc[1][0], 0, 0, 0);
        acc[1][1] = __builtin_amdgcn_mfma_f32_16x16x32_bf16(ah1, bh1, acc[1][1], 0, 0, 0);
        acc[0][0] = __builtin_amdgcn_mfma_f32_16x16x32_bf16(ah0, bl0, acc[0][0], 0, 0, 0);
        acc[0][1] = __builtin_amdgcn_mfma_f32_16x16x32_bf16(ah0, bl1, acc[0][1], 0, 0, 0);
        acc[1][0] = __builtin_amdgcn_mfma_f32_16x16x32_bf16(ah1, bl0, acc[1][0], 0, 0, 0);
        acc[1][1] = __builtin_amdgcn_mfma_f32_16x16x32_bf16(ah1, bl1, acc[1][1], 0, 0, 0);
        acc[0][0] = __builtin_amdgcn_mfma_f32_16x16x32_bf16(al0, bh0, acc[0][0], 0, 0, 0);
        acc[0][1] = __builtin_amdgcn_mfma_f32_16x16x32_bf16(al0, bh1, acc[0][1], 0, 0, 0);
        acc[1][0] = __builtin_amdgcn_mfma_f32_16x16x32_bf16(al1, bh0, acc[1][0], 0, 0, 0);
        acc[1][1] = __builtin_amdgcn_mfma_f32_16x16x32_bf16(al1, bh1, acc[1][1], 0, 0, 0);
    }

#pragma unroll
    for (int i = 0; i < 2; ++i)
#pragma unroll
        for (int j = 0; j < 2; ++j) {
            const int m = msub0 + i * 16 + quad * 4;
            const int n = nsub0 + j * 16 + l16;
#pragma unroll
            for (int r = 0; r < 4; ++r) LdsF[m + r][n] = acc[i][j][r];
        }
    __syncthreads();
    const int m = t >> 2, nb = (t & 3) * 16;
    const float bv = bias[row0 + m];
    float* dst = y + ((size_t)b * 256 + row0 + m) * N + col0 + nb;
#pragma unroll
    for (int g = 0; g < 4; ++g) {
        float4 o4;
        o4.x = LdsF[m][nb + g * 4 + 0] + bv;
        o4.y = LdsF[m][nb + g * 4 + 1] + bv;
        o4.z = LdsF[m][nb + g * 4 + 2] + bv;
        o4.w = LdsF[m][nb + g * 4 + 3] + bv;
        *(float4*)(dst + g * 4) = o4;
    }
}

extern "C" void kernel_launch(void* const* d_in, const int* in_sizes, int n_in,
                              void* d_out, int out_size, void* d_ws, size_t ws_size,
                              hipStream_t stream) {
    const float* x     = (const float*)d_in[0];  // (4,256,64,64)
    const float* w_qkv = (const float*)d_in[1];  // (384,256)
    const float* w_out = (const float*)d_in[2];  // (256,128)
    const float* b_out = (const float*)d_in[3];  // (256,)
    float* y = (float*)d_out;                    // (4,256,64,64)

    // workspace 47.7 MB (<= 50.3 MB proven in R2), with overlays:
    //   [0, 16.78 MB)       Xth+Xtl (bf16)  -> after gemm1: OpA (attn segs 0,1)
    //   [16.78, 17.30 MB)   Wqh,Wql,Woh,Wol
    //   [17.30, 29.88 MB)   Qp,Kp,Vp        -> after attn: Oth,Otl (8.4 MB)
    //   [29.88, 46.66 MB)   OpB (attn segs 2,3)
    //   [46.66, 47.71 MB)   Lpart (4 x 16 x 4096 f32)
    char* base = (char*)d_ws;
    unsigned short* Xth = (unsigned short*)base;                     // 4.19M el
    unsigned short* Xtl = Xth + (size_t)BATCH * N_TOK * 256;
    unsigned short* Wqh = (unsigned short*)(base + 16777216);
    unsigned short* Wql = Wqh + 98304;
    unsigned short* Woh = Wql + 98304;
    unsigned short* Wol = Woh + 32768;
    unsigned short* Qp  = (unsigned short*)(base + 17301504);
    unsigned short* Kp  = Qp + (size_t)16 * N_TOK * 32;
    unsigned short* Vp  = Kp + (size_t)16 * N_TOK * 32;
    float* OpA   = (float*)base;                                     // overlay Xt
    float* OpB   = (float*)(base + 29884416);
    float* Lpart = (float*)(base + 46661632);
    unsigned short* Oth = Qp;                                        // overlay packs
    unsigned short* Otl = Oth + (size_t)BATCH * N_TOK * 128;

    dim3 blk(256);
    convert_w<<<dim3(128), blk, 0, stream>>>(w_qkv, w_out, Wqh, Wql, Woh, Wol);
    convert_x<<<dim3(64, 4, BATCH), blk, 0, stream>>>(x, Xth, Xtl);
    gemm1_mfma<<<dim3(64, 6, BATCH), blk, 0, stream>>>(
        Wqh, Wql, Xth, Xtl, Qp, Kp, Vp);
    attn_mfma<<<dim3(32, 4, 16), blk, 0, stream>>>(Qp, Kp, Vp, OpA, OpB, Lpart);
    combine_kernel<<<dim3(64, BATCH), blk, 0, stream>>>(OpA, OpB, Lpart, Oth, Otl);
    gemm2_mfma<<<dim3(64, 4, BATCH), blk, 0, stream>>>(
        Woh, Wol, Oth, Otl, b_out, y);
}

// Round 7
// 221.632 us; speedup vs baseline: 1.1143x; 1.1143x over previous
//
#include <hip/hip_runtime.h>

#define N_TOK 4096
#define BATCH 4

typedef __attribute__((ext_vector_type(8))) short short8;
typedef __attribute__((ext_vector_type(4))) float floatx4;

// Pack two floats to packed bf16 pair (round-half-away) in 3 VALU ops:
// bits+0x8000 then v_perm_b32 selecting the two high halves.
__device__ __forceinline__ unsigned pack_rnd(float a, float b) {
    unsigned ra = __float_as_uint(a) + 0x8000u;
    unsigned rb = __float_as_uint(b) + 0x8000u;
    return __builtin_amdgcn_perm(rb, ra, 0x07060302u);
}

// Split two floats into bf16 hi-pair and lo-pair (hi round-half-away,
// lo = exact remainder rounded).  ~9 VALU ops per pair.
__device__ __forceinline__ void split_pack(float a, float b,
                                           unsigned &ph, unsigned &pl) {
    unsigned ra = __float_as_uint(a) + 0x8000u;
    unsigned rb = __float_as_uint(b) + 0x8000u;
    ph = __builtin_amdgcn_perm(rb, ra, 0x07060302u);
    float la = a - __uint_as_float(ra & 0xffff0000u);
    float lb = b - __uint_as_float(rb & 0xffff0000u);
    pl = __builtin_amdgcn_perm(__float_as_uint(lb) + 0x8000u,
                               __float_as_uint(la) + 0x8000u, 0x07060302u);
}

__device__ __forceinline__ float fast_exp2(float x) {
#if __has_builtin(__builtin_amdgcn_exp2f)
    return __builtin_amdgcn_exp2f(x);   // v_exp_f32: ~8 cyc/wave (R5/R6 A/B)
#else
    return exp2f(x);
#endif
}

// ---------------------------------------------------------------------------
// Fused conversions (one launch):
//   blocks 0..1023:  x fp32 [b][k=256][n] -> bf16 hi/lo X^T [b][n][k]
//   blocks 1024..1151: w_qkv + w_out -> bf16 hi/lo (layout preserved)
// ---------------------------------------------------------------------------
__global__ __launch_bounds__(256) void convert_wx(
    const float* __restrict__ x,
    const float* __restrict__ wq, const float* __restrict__ wo,
    unsigned short* __restrict__ Xth, unsigned short* __restrict__ Xtl,
    unsigned short* __restrict__ Wqh, unsigned short* __restrict__ Wql,
    unsigned short* __restrict__ Woh, unsigned short* __restrict__ Wol)
{
    const int t = threadIdx.x;
    const int bx = blockIdx.x;
    if (bx >= 1024) {
        const int idx = (bx - 1024) * 256 + t;   // float4 group
        const float* src; unsigned short *dh, *dl; int off;
        if (idx < 24576) { src = wq; dh = Wqh; dl = Wql; off = idx * 4; }
        else             { src = wo; dh = Woh; dl = Wol; off = (idx - 24576) * 4; }
        float4 v = *(const float4*)(src + off);
        uint2 ph, pl;
        split_pack(v.x, v.y, ph.x, pl.x);
        split_pack(v.z, v.w, ph.y, pl.y);
        *(uint2*)(dh + off) = ph;
        *(uint2*)(dl + off) = pl;
        return;
    }
    const int N = N_TOK;
    const int b = bx >> 8;
    const int k0 = ((bx >> 6) & 3) * 64;
    const int n0 = (bx & 63) * 64;

    __shared__ float Lx[64][68];

    {
        const int kr = t >> 2, nb = (t & 3) * 16;
        const float* src = x + ((size_t)b * 256 + k0 + kr) * N + n0 + nb;
#pragma unroll
        for (int j = 0; j < 4; ++j)
            *(float4*)&Lx[kr][nb + j * 4] = *(const float4*)(src + j * 4);
    }
    __syncthreads();
    {
        const int nr = t >> 2, kb = (t & 3) * 16;
        unsigned ph[8], pl[8];
#pragma unroll
        for (int q = 0; q < 8; ++q)
            split_pack(Lx[kb + 2 * q][nr], Lx[kb + 2 * q + 1][nr], ph[q], pl[q]);
        unsigned short* dh = Xth + ((size_t)b * N + n0 + nr) * 256 + k0 + kb;
        unsigned short* dl = Xtl + ((size_t)b * N + n0 + nr) * 256 + k0 + kb;
        *(uint4*)&dh[0] = *(uint4*)&ph[0];
        *(uint4*)&dh[8] = *(uint4*)&ph[4];
        *(uint4*)&dl[0] = *(uint4*)&pl[0];
        *(uint4*)&dl[8] = *(uint4*)&pl[4];
    }
}

// ---------------------------------------------------------------------------
// QKV GEMM, split-bf16 MFMA (3-term), direct-global frags, fused pack
// epilogue (R6 structure; packs via pack_rnd).
// ---------------------------------------------------------------------------
__global__ __launch_bounds__(256) void gemm1_mfma(
    const unsigned short* __restrict__ Wqh, const unsigned short* __restrict__ Wql,
    const unsigned short* __restrict__ Xth, const unsigned short* __restrict__ Xtl,
    unsigned short* __restrict__ Qp, unsigned short* __restrict__ Kp,
    unsigned short* __restrict__ Vp)
{
    const int N = N_TOK;
    const int b = blockIdx.z;
    const int row0 = blockIdx.y * 64;
    const int col0 = blockIdx.x * 64;
    const int t = threadIdx.x;
    const int wave = t >> 6, lane = t & 63;
    const int l16 = lane & 15, quad = lane >> 4;
    const int msub0 = (wave & 1) * 32, nsub0 = (wave >> 1) * 32;

    __shared__ unsigned short LdsT[64][68];
    __shared__ float LdsF[64][68];

    const unsigned short* aH = Wqh + (size_t)(row0 + msub0 + l16) * 256 + quad * 8;
    const unsigned short* aL = Wql + (size_t)(row0 + msub0 + l16) * 256 + quad * 8;
    const unsigned short* bH = Xth + ((size_t)b * N + col0 + nsub0 + l16) * 256 + quad * 8;
    const unsigned short* bL = Xtl + ((size_t)b * N + col0 + nsub0 + l16) * 256 + quad * 8;

    floatx4 acc[2][2] = {};
#pragma unroll
    for (int ks = 0; ks < 8; ++ks) {
        short8 ah0 = *(const short8*)(aH + ks * 32);
        short8 ah1 = *(const short8*)(aH + 16 * 256 + ks * 32);
        short8 al0 = *(const short8*)(aL + ks * 32);
        short8 al1 = *(const short8*)(aL + 16 * 256 + ks * 32);
        short8 bh0 = *(const short8*)(bH + ks * 32);
        short8 bh1 = *(const short8*)(bH + 16 * 256 + ks * 32);
        short8 bl0 = *(const short8*)(bL + ks * 32);
        short8 bl1 = *(const short8*)(bL + 16 * 256 + ks * 32);
        acc[0][0] = __builtin_amdgcn_mfma_f32_16x16x32_bf16(ah0, bh0, acc[0][0], 0, 0, 0);
        acc[0][1] = __builtin_amdgcn_mfma_f32_16x16x32_bf16(ah0, bh1, acc[0][1], 0, 0, 0);
        acc[1][0] = __builtin_amdgcn_mfma_f32_16x16x32_bf16(ah1, bh0, acc[1][0], 0, 0, 0);
        acc[1][1] = __builtin_amdgcn_mfma_f32_16x16x32_bf16(ah1, bh1, acc[1][1], 0, 0, 0);
        acc[0][0] = __builtin_amdgcn_mfma_f32_16x16x32_bf16(ah0, bl0, acc[0][0], 0, 0, 0);
        acc[0][1] = __builtin_amdgcn_mfma_f32_16x16x32_bf16(ah0, bl1, acc[0][1], 0, 0, 0);
        acc[1][0] = __builtin_amdgcn_mfma_f32_16x16x32_bf16(ah1, bl0, acc[1][0], 0, 0, 0);
        acc[1][1] = __builtin_amdgcn_mfma_f32_16x16x32_bf16(ah1, bl1, acc[1][1], 0, 0, 0);
        acc[0][0] = __builtin_amdgcn_mfma_f32_16x16x32_bf16(al0, bh0, acc[0][0], 0, 0, 0);
        acc[0][1] = __builtin_amdgcn_mfma_f32_16x16x32_bf16(al0, bh1, acc[0][1], 0, 0, 0);
        acc[1][0] = __builtin_amdgcn_mfma_f32_16x16x32_bf16(al1, bh0, acc[1][0], 0, 0, 0);
        acc[1][1] = __builtin_amdgcn_mfma_f32_16x16x32_bf16(al1, bh1, acc[1][1], 0, 0, 0);
    }

    const int region = row0 >> 7;   // 0=Q, 1=K, 2=V
    if (region == 2) {
#pragma unroll
        for (int i = 0; i < 2; ++i)
#pragma unroll
            for (int j = 0; j < 2; ++j) {
                const int m = msub0 + i * 16 + quad * 4;
                const int n = nsub0 + j * 16 + l16;
#pragma unroll
                for (int r = 0; r < 4; ++r) LdsF[m + r][n] = acc[i][j][r];
            }
        __syncthreads();
        const int m = t >> 2, nb = (t & 3) * 16;
        const int vrow = b * 128 + (row0 - 256) + m;
        unsigned pk[8];
#pragma unroll
        for (int q = 0; q < 8; ++q)
            pk[q] = pack_rnd(LdsF[m][nb + 2 * q], LdsF[m][nb + 2 * q + 1]);
        unsigned short* dst = Vp + (size_t)vrow * N + col0 + nb;
        *(uint4*)&dst[0] = *(uint4*)&pk[0];
        *(uint4*)&dst[8] = *(uint4*)&pk[4];
    } else {
        const float sc = region ? 1.0f
                                : (0.17677669529663687f * 1.4426950408889634f);
#pragma unroll
        for (int i = 0; i < 2; ++i)
#pragma unroll
            for (int j = 0; j < 2; ++j) {
                const int m = msub0 + i * 16 + quad * 4;
                const int n = nsub0 + j * 16 + l16;
                uint2 pr;
                pr.x = pack_rnd(acc[i][j][0] * sc, acc[i][j][1] * sc);
                pr.y = pack_rnd(acc[i][j][2] * sc, acc[i][j][3] * sc);
                *(uint2*)&LdsT[n][m] = pr;
            }
        __syncthreads();
        const int n = t & 63, hb = (t >> 6) & 1, dh = t >> 7;
        const int h = ((row0 & 127) >> 5) + hb;
        const int m0 = hb * 32 + dh * 16;
        unsigned tmp[8];
        *(uint2*)&tmp[0] = *(const uint2*)&LdsT[n][m0];
        *(uint2*)&tmp[2] = *(const uint2*)&LdsT[n][m0 + 4];
        *(uint2*)&tmp[4] = *(const uint2*)&LdsT[n][m0 + 8];
        *(uint2*)&tmp[6] = *(const uint2*)&LdsT[n][m0 + 12];
        unsigned short* dst = (region ? Kp : Qp) +
            ((size_t)(b * 4 + h) * N + col0 + n) * 32 + dh * 16;
        *(uint4*)&dst[0] = *(uint4*)&tmp[0];
        *(uint4*)&dst[8] = *(uint4*)&tmp[4];
    }
}

// ---------------------------------------------------------------------------
// MFMA flash attention (R5 structure: v_exp_f32, fixed max, key-split 4-way,
// l via MFMA ones) with perm-trick P packing (3 insts/pair).
// ---------------------------------------------------------------------------
__global__ __launch_bounds__(256) void attn_mfma(
    const unsigned short* __restrict__ QpH,
    const unsigned short* __restrict__ KpH,
    const unsigned short* __restrict__ VpH,
    float* __restrict__ OpA, float* __restrict__ OpB,
    float* __restrict__ Lpart)
{
    const int N = N_TOK;
    const int bh = blockIdx.z;
    const int seg = blockIdx.y;
    const int i0 = blockIdx.x * 128;
    const int j0 = seg * 1024;
    const int t = threadIdx.x;
    const int wave = t >> 6, lane = t & 63;
    const int l16 = lane & 15, quad = lane >> 4;

    __shared__ unsigned short KsH[64][40];
    __shared__ unsigned short VsH[32][72];
    __shared__ unsigned short Pt[4][32][72];

    short8 ones;
#pragma unroll
    for (int e = 0; e < 8; ++e) ones[e] = (short)0x3F80;

    short8 qh[2];
#pragma unroll
    for (int g = 0; g < 2; ++g)
        qh[g] = *(const short8*)(QpH +
            ((size_t)bh * N + i0 + wave * 32 + g * 16 + l16) * 32 + quad * 8);

    floatx4 o[2][2] = {};
    floatx4 lacc[2] = {};

    const int skey = t >> 2, sdp = (t & 3) * 8;
    const unsigned short* kp = KpH + ((size_t)bh * N + j0 + skey) * 32 + sdp;
    const int svd = t >> 3, svp = (t & 7) * 8;
    const unsigned short* vp = VpH + ((size_t)bh * 32 + svd) * N + j0 + svp;

    short8 kreg = *(const short8*)kp;
    short8 vreg = *(const short8*)vp;

    for (int it = 0; it < 16; ++it) {
        __syncthreads();
        *(short8*)&KsH[skey][sdp] = kreg;
        *(short8*)&VsH[svd][svp] = vreg;
        __syncthreads();

        if (it + 1 < 16) {
            kp += 64 * 32; vp += 64;
            kreg = *(const short8*)kp;
            vreg = *(const short8*)vp;
        }

        short8 kh0 = *(const short8*)&KsH[ 0 + l16][quad * 8];
        short8 kh1 = *(const short8*)&KsH[16 + l16][quad * 8];
        short8 kh2 = *(const short8*)&KsH[32 + l16][quad * 8];
        short8 kh3 = *(const short8*)&KsH[48 + l16][quad * 8];

#pragma unroll
        for (int g = 0; g < 2; ++g) {
            const floatx4 z = {0.0f, 0.0f, 0.0f, 0.0f};
            floatx4 st[4];
            st[0] = __builtin_amdgcn_mfma_f32_16x16x32_bf16(kh0, qh[g], z, 0, 0, 0);
            st[1] = __builtin_amdgcn_mfma_f32_16x16x32_bf16(kh1, qh[g], z, 0, 0, 0);
            st[2] = __builtin_amdgcn_mfma_f32_16x16x32_bf16(kh2, qh[g], z, 0, 0, 0);
            st[3] = __builtin_amdgcn_mfma_f32_16x16x32_bf16(kh3, qh[g], z, 0, 0, 0);

#pragma unroll
            for (int s = 0; s < 4; ++s) {
                float p0 = fast_exp2(st[s][0]);
                float p1 = fast_exp2(st[s][1]);
                float p2 = fast_exp2(st[s][2]);
                float p3 = fast_exp2(st[s][3]);
                uint2 pr;
                pr.x = pack_rnd(p0, p1);
                pr.y = pack_rnd(p2, p3);
                *(uint2*)&Pt[wave][g * 16 + l16][s * 16 + quad * 4] = pr;
            }
        }

#pragma unroll
        for (int ks = 0; ks < 2; ++ks) {
            short8 pf0 = *(const short8*)&Pt[wave][ 0 + l16][ks * 32 + quad * 8];
            short8 pf1 = *(const short8*)&Pt[wave][16 + l16][ks * 32 + quad * 8];
            short8 vh0 = *(const short8*)&VsH[ 0 + l16][ks * 32 + quad * 8];
            short8 vh1 = *(const short8*)&VsH[16 + l16][ks * 32 + quad * 8];
            o[0][0] = __builtin_amdgcn_mfma_f32_16x16x32_bf16(vh0, pf0, o[0][0], 0, 0, 0);
            o[0][1] = __builtin_amdgcn_mfma_f32_16x16x32_bf16(vh1, pf0, o[0][1], 0, 0, 0);
            o[1][0] = __builtin_amdgcn_mfma_f32_16x16x32_bf16(vh0, pf1, o[1][0], 0, 0, 0);
            o[1][1] = __builtin_amdgcn_mfma_f32_16x16x32_bf16(vh1, pf1, o[1][1], 0, 0, 0);
            lacc[0] = __builtin_amdgcn_mfma_f32_16x16x32_bf16(ones, pf0, lacc[0], 0, 0, 0);
            lacc[1] = __builtin_amdgcn_mfma_f32_16x16x32_bf16(ones, pf1, lacc[1], 0, 0, 0);
        }
    }

    float* OP = (seg < 2) ? OpA : OpB;
    const int segl = seg & 1;
#pragma unroll
    for (int g = 0; g < 2; ++g) {
        const int n = i0 + wave * 32 + g * 16 + l16;
#pragma unroll
        for (int half = 0; half < 2; ++half)
#pragma unroll
            for (int r = 0; r < 4; ++r) {
                const int d = half * 16 + quad * 4 + r;
                OP[((size_t)segl * 512 + bh * 32 + d) * N + n] = o[g][half][r];
            }
        Lpart[((size_t)seg * 16 + bh) * N + n] = lacc[g][0];
    }
}

// ---------------------------------------------------------------------------
// Combine 4 key-segments, normalize, transpose to Ot[b][n][c=128] bf16 hi/lo
// (gemm2 B-operand layout).  Packs via split_pack.
// ---------------------------------------------------------------------------
__global__ __launch_bounds__(256) void combine_kernel(
    const float* __restrict__ OpA, const float* __restrict__ OpB,
    const float* __restrict__ Lpart,
    unsigned short* __restrict__ Oth, unsigned short* __restrict__ Otl)
{
    const int N = N_TOK;
    const int b = blockIdx.y;
    const int n0 = blockIdx.x * 64;
    const int t = threadIdx.x;

    __shared__ float Ls[128][68];

    {
        const int c = t >> 1, nh = (t & 1) * 32;
        const int h = c >> 5;
        float acc[32], lsum[32];
#pragma unroll
        for (int i = 0; i < 32; i += 4) {
            *(float4*)&acc[i] = *(const float4*)&OpA[((size_t)(b * 128 + c)) * N + n0 + nh + i];
            *(float4*)&lsum[i] = *(const float4*)&Lpart[((size_t)(b * 4 + h)) * N + n0 + nh + i];
        }
#pragma unroll
        for (int s = 1; s < 4; ++s) {
            const float* base = (s < 2) ? OpA : OpB;
            const size_t row = (size_t)(s & 1) * 512 + b * 128 + c;
            const size_t lrow = (size_t)s * 16 + b * 4 + h;
#pragma unroll
            for (int i = 0; i < 32; i += 4) {
                float4 o4 = *(const float4*)&base[row * N + n0 + nh + i];
                float4 l4 = *(const float4*)&Lpart[lrow * N + n0 + nh + i];
                acc[i] += o4.x; acc[i+1] += o4.y; acc[i+2] += o4.z; acc[i+3] += o4.w;
                lsum[i] += l4.x; lsum[i+1] += l4.y; lsum[i+2] += l4.z; lsum[i+3] += l4.w;
            }
        }
#pragma unroll
        for (int i = 0; i < 32; ++i) Ls[c][nh + i] = acc[i] / lsum[i];
    }
    __syncthreads();
#pragma unroll
    for (int u = 0; u < 2; ++u) {
        const int idx = t * 2 + u;
        const int n = idx >> 3, cc = (idx & 7) * 16;
        unsigned ph[8], pl[8];
#pragma unroll
        for (int q = 0; q < 8; ++q)
            split_pack(Ls[cc + 2 * q][n], Ls[cc + 2 * q + 1][n], ph[q], pl[q]);
        unsigned short* dh = Oth + ((size_t)b * N + n0 + n) * 128 + cc;
        unsigned short* dl = Otl + ((size_t)b * N + n0 + n) * 128 + cc;
        *(uint4*)&dh[0] = *(uint4*)&ph[0];
        *(uint4*)&dh[8] = *(uint4*)&ph[4];
        *(uint4*)&dl[0] = *(uint4*)&pl[0];
        *(uint4*)&dl[8] = *(uint4*)&pl[4];
    }
}

// ---------------------------------------------------------------------------
// Output GEMM, split-bf16 MFMA (3-term), + bias (R6 structure).
// ---------------------------------------------------------------------------
__global__ __launch_bounds__(256) void gemm2_mfma(
    const unsigned short* __restrict__ Woh, const unsigned short* __restrict__ Wol,
    const unsigned short* __restrict__ Oth, const unsigned short* __restrict__ Otl,
    const float* __restrict__ bias, float* __restrict__ y)
{
    const int N = N_TOK;
    const int b = blockIdx.z;
    const int row0 = blockIdx.y * 64;
    const int col0 = blockIdx.x * 64;
    const int t = threadIdx.x;
    const int wave = t >> 6, lane = t & 63;
    const int l16 = lane & 15, quad = lane >> 4;
    const int msub0 = (wave & 1) * 32, nsub0 = (wave >> 1) * 32;

    __shared__ float LdsF[64][68];

    const unsigned short* aH = Woh + (size_t)(row0 + msub0 + l16) * 128 + quad * 8;
    const unsigned short* aL = Wol + (size_t)(row0 + msub0 + l16) * 128 + quad * 8;
    const unsigned short* bH = Oth + ((size_t)b * N + col0 + nsub0 + l16) * 128 + quad * 8;
    const unsigned short* bL = Otl + ((size_t)b * N + col0 + nsub0 + l16) * 128 + quad * 8;

    floatx4 acc[2][2] = {};
#pragma unroll
    for (int ks = 0; ks < 4; ++ks) {
        short8 ah0 = *(const short8*)(aH + ks * 32);
        short8 ah1 = *(const short8*)(aH + 16 * 128 + ks * 32);
        short8 al0 = *(const short8*)(aL + ks * 32);
        short8 al1 = *(const short8*)(aL + 16 * 128 + ks * 32);
        short8 bh0 = *(const short8*)(bH + ks * 32);
        short8 bh1 = *(const short8*)(bH + 16 * 128 + ks * 32);
        short8 bl0 = *(const short8*)(bL + ks * 32);
        short8 bl1 = *(const short8*)(bL + 16 * 128 + ks * 32);
        acc[0][0] = __builtin_amdgcn_mfma_f32_16x16x32_bf16(ah0, bh0, acc[0][0], 0, 0, 0);
        acc[0][1] = __builtin_amdgcn_mfma_f32_16x16x32_bf16(ah0, bh1, acc[0][1], 0, 0, 0);
        acc[1][0] = __builtin_amdgcn_mfma_f32_16x16x32_bf16(ah1, bh0, acc[1][0], 0, 0, 0);
        acc[1][1] = __builtin_amdgcn_mfma_f32_16x16x32_bf16(ah1, bh1, acc[1][1], 0, 0, 0);
        acc[0][0] = __builtin_amdgcn_mfma_f32_16x16x32_bf16(ah0, bl0, acc[0][0], 0, 0, 0);
        acc[0][1] = __builtin_amdgcn_mfma_f32_16x16x32_bf16(ah0, bl1, acc[0][1], 0, 0, 0);
        acc[1][0] = __builtin_amdgcn_mfma_f32_16x16x32_bf16(ah1, bl0, acc[1][0], 0, 0, 0);
        acc[1][1] = __builtin_amdgcn_mfma_f32_16x16x32_bf16(ah1, bl1, acc[1][1], 0, 0, 0);
        acc[0][0] = __builtin_amdgcn_mfma_f32_16x16x32_bf16(al0, bh0, acc[0][0], 0, 0, 0);
        acc[0][1] = __builtin_amdgcn_mfma_f32_16x16x32_bf16(al0, bh1, acc[0][1], 0, 0, 0);
        acc[1][0] = __builtin_amdgcn_mfma_f32_16x16x32_bf16(al1, bh0, acc[1][0], 0, 0, 0);
        acc[1][1] = __builtin_amdgcn_mfma_f32_16x16x32_bf16(al1, bh1, acc[1][1], 0, 0, 0);
    }

#pragma unroll
    for (int i = 0; i < 2; ++i)
#pragma unroll
        for (int j = 0; j < 2; ++j) {
            const int m = msub0 + i * 16 + quad * 4;
            const int n = nsub0 + j * 16 + l16;
#pragma unroll
            for (int r = 0; r < 4; ++r) LdsF[m + r][n] = acc[i][j][r];
        }
    __syncthreads();
    const int m = t >> 2, nb = (t & 3) * 16;
    const float bv = bias[row0 + m];
    float* dst = y + ((size_t)b * 256 + row0 + m) * N + col0 + nb;
#pragma unroll
    for (int g = 0; g < 4; ++g) {
        float4 o4;
        o4.x = LdsF[m][nb + g * 4 + 0] + bv;
        o4.y = LdsF[m][nb + g * 4 + 1] + bv;
        o4.z = LdsF[m][nb + g * 4 + 2] + bv;
        o4.w = LdsF[m][nb + g * 4 + 3] + bv;
        *(float4*)(dst + g * 4) = o4;
    }
}

extern "C" void kernel_launch(void* const* d_in, const int* in_sizes, int n_in,
                              void* d_out, int out_size, void* d_ws, size_t ws_size,
                              hipStream_t stream) {
    const float* x     = (const float*)d_in[0];
    const float* w_qkv = (const float*)d_in[1];
    const float* w_out = (const float*)d_in[2];
    const float* b_out = (const float*)d_in[3];
    float* y = (float*)d_out;

    // workspace layout identical to R6 (47.7 MB)
    char* base = (char*)d_ws;
    unsigned short* Xth = (unsigned short*)base;
    unsigned short* Xtl = Xth + (size_t)BATCH * N_TOK * 256;
    unsigned short* Wqh = (unsigned short*)(base + 16777216);
    unsigned short* Wql = Wqh + 98304;
    unsigned short* Woh = Wql + 98304;
    unsigned short* Wol = Woh + 32768;
    unsigned short* Qp  = (unsigned short*)(base + 17301504);
    unsigned short* Kp  = Qp + (size_t)16 * N_TOK * 32;
    unsigned short* Vp  = Kp + (size_t)16 * N_TOK * 32;
    float* OpA   = (float*)base;
    float* OpB   = (float*)(base + 29884416);
    float* Lpart = (float*)(base + 46661632);
    unsigned short* Oth = Qp;
    unsigned short* Otl = Oth + (size_t)BATCH * N_TOK * 128;

    dim3 blk(256);
    convert_wx<<<dim3(1152), blk, 0, stream>>>(
        x, w_qkv, w_out, Xth, Xtl, Wqh, Wql, Woh, Wol);
    gemm1_mfma<<<dim3(64, 6, BATCH), blk, 0, stream>>>(
        Wqh, Wql, Xth, Xtl, Qp, Kp, Vp);
    attn_mfma<<<dim3(32, 4, 16), blk, 0, stream>>>(Qp, Kp, Vp, OpA, OpB, Lpart);
    combine_kernel<<<dim3(64, BATCH), blk, 0, stream>>>(OpA, OpB, Lpart, Oth, Otl);
    gemm2_mfma<<<dim3(64, 4, BATCH), blk, 0, stream>>>(
        Woh, Wol, Oth, Otl, b_out, y);
}

// Round 8
// 197.339 us; speedup vs baseline: 1.2515x; 1.1231x over previous
//
#include <hip/hip_runtime.h>

#define N_TOK 4096
#define BATCH 4

typedef __attribute__((ext_vector_type(8))) short short8;
typedef __attribute__((ext_vector_type(4))) float floatx4;

// Pack two floats to packed bf16 pair (round-half-away): 3 VALU ops.
__device__ __forceinline__ unsigned pack_rnd(float a, float b) {
    unsigned ra = __float_as_uint(a) + 0x8000u;
    unsigned rb = __float_as_uint(b) + 0x8000u;
    return __builtin_amdgcn_perm(rb, ra, 0x07060302u);
}

// Split two floats into bf16 hi-pair and lo-pair.
__device__ __forceinline__ void split_pack(float a, float b,
                                           unsigned &ph, unsigned &pl) {
    unsigned ra = __float_as_uint(a) + 0x8000u;
    unsigned rb = __float_as_uint(b) + 0x8000u;
    ph = __builtin_amdgcn_perm(rb, ra, 0x07060302u);
    float la = a - __uint_as_float(ra & 0xffff0000u);
    float lb = b - __uint_as_float(rb & 0xffff0000u);
    pl = __builtin_amdgcn_perm(__float_as_uint(lb) + 0x8000u,
                               __float_as_uint(la) + 0x8000u, 0x07060302u);
}

__device__ __forceinline__ float fast_exp2(float x) {
#if __has_builtin(__builtin_amdgcn_exp2f)
    return __builtin_amdgcn_exp2f(x);
#else
    return exp2f(x);
#endif
}

// ---------------------------------------------------------------------------
// Convert weights to bf16 hi/lo (layout preserved).  128 blocks.
// ---------------------------------------------------------------------------
__global__ __launch_bounds__(256) void convert_w(
    const float* __restrict__ wq, const float* __restrict__ wo,
    unsigned short* __restrict__ Wqh, unsigned short* __restrict__ Wql,
    unsigned short* __restrict__ Woh, unsigned short* __restrict__ Wol)
{
    const int idx = blockIdx.x * 256 + threadIdx.x;   // float4 group
    const float* src; unsigned short *dh, *dl; int off;
    if (idx < 24576) { src = wq; dh = Wqh; dl = Wql; off = idx * 4; }
    else             { src = wo; dh = Woh; dl = Wol; off = (idx - 24576) * 4; }
    float4 v = *(const float4*)(src + off);
    uint2 ph, pl;
    split_pack(v.x, v.y, ph.x, pl.x);
    split_pack(v.z, v.w, ph.y, pl.y);
    *(uint2*)(dh + off) = ph;
    *(uint2*)(dl + off) = pl;
}

// ---------------------------------------------------------------------------
// QKV GEMM with fused x-conversion.  Per 64-k chunk: coalesced fp32 load of
// x[k][n] -> LDS, transpose+split to bf16 hi/lo [n][k] LDS operands
// ([64][40]-stride frag layout, proven in attn), 3-term split-bf16 MFMA.
// A (weights hi/lo) direct from global (L2-resident).  Fused pack epilogue:
//   Q: Qp[bh][n][d] * (1/sqrt(32))*log2(e);  K: Kp[bh][n][d];  V: Vp[c][n].
// Grid (64 n, 6 m, 4 b), 256 threads (4 waves, each 32m x 32n).
// ---------------------------------------------------------------------------
__global__ __launch_bounds__(256) void gemm1_fused(
    const unsigned short* __restrict__ Wqh, const unsigned short* __restrict__ Wql,
    const float* __restrict__ x,
    unsigned short* __restrict__ Qp, unsigned short* __restrict__ Kp,
    unsigned short* __restrict__ Vp)
{
    const int N = N_TOK;
    const int b = blockIdx.z;
    const int row0 = blockIdx.y * 64;
    const int col0 = blockIdx.x * 64;
    const int t = threadIdx.x;
    const int wave = t >> 6, lane = t & 63;
    const int l16 = lane & 15, quad = lane >> 4;
    const int msub0 = (wave & 1) * 32, nsub0 = (wave >> 1) * 32;

    __shared__ __align__(16) char smem[37888];
    float (*Xf)[68] = (float(*)[68])smem;                       // [64][68] fp32
    unsigned short* XsB = (unsigned short*)(smem + 17408);      // 4 x [64][40]
    // layout (elements): H(ks=0)@0, L0@2560, H1@5120, L1@7680

    const unsigned short* aH = Wqh + (size_t)(row0 + msub0 + l16) * 256 + quad * 8;
    const unsigned short* aL = Wql + (size_t)(row0 + msub0 + l16) * 256 + quad * 8;

    floatx4 acc[2][2] = {};

    const int kr = t >> 2, nb = (t & 3) * 16;        // fp32 load role
    const int nr = t >> 2, kb = (t & 3) * 16;        // transpose role

    for (int kc = 0; kc < 4; ++kc) {
        __syncthreads();   // Xs/Xf free (prev chunk's readers done)
        {
            const float* src = x + ((size_t)b * 256 + kc * 64 + kr) * N + col0 + nb;
#pragma unroll
            for (int j = 0; j < 4; ++j)
                *(float4*)&Xf[kr][nb + j * 4] = *(const float4*)(src + j * 4);
        }
        __syncthreads();
        {
            unsigned ph[8], pl[8];
#pragma unroll
            for (int q = 0; q < 8; ++q)
                split_pack(Xf[kb + 2 * q][nr], Xf[kb + 2 * q + 1][nr], ph[q], pl[q]);
            unsigned short* dH = XsB + (kb >> 5) * 5120 + nr * 40 + (kb & 31);
            unsigned short* dL = dH + 2560;
            *(uint4*)&dH[0] = *(uint4*)&ph[0];
            *(uint4*)&dH[8] = *(uint4*)&ph[4];
            *(uint4*)&dL[0] = *(uint4*)&pl[0];
            *(uint4*)&dL[8] = *(uint4*)&pl[4];
        }
        __syncthreads();
#pragma unroll
        for (int ks = 0; ks < 2; ++ks) {
            const unsigned short* bb = XsB + ks * 5120;
            short8 bh0 = *(const short8*)(bb + (nsub0 + l16) * 40 + quad * 8);
            short8 bh1 = *(const short8*)(bb + (nsub0 + 16 + l16) * 40 + quad * 8);
            short8 bl0 = *(const short8*)(bb + 2560 + (nsub0 + l16) * 40 + quad * 8);
            short8 bl1 = *(const short8*)(bb + 2560 + (nsub0 + 16 + l16) * 40 + quad * 8);
            const int kg = kc * 64 + ks * 32;
            short8 ah0 = *(const short8*)(aH + kg);
            short8 ah1 = *(const short8*)(aH + 16 * 256 + kg);
            short8 al0 = *(const short8*)(aL + kg);
            short8 al1 = *(const short8*)(aL + 16 * 256 + kg);
            acc[0][0] = __builtin_amdgcn_mfma_f32_16x16x32_bf16(ah0, bh0, acc[0][0], 0, 0, 0);
            acc[0][1] = __builtin_amdgcn_mfma_f32_16x16x32_bf16(ah0, bh1, acc[0][1], 0, 0, 0);
            acc[1][0] = __builtin_amdgcn_mfma_f32_16x16x32_bf16(ah1, bh0, acc[1][0], 0, 0, 0);
            acc[1][1] = __builtin_amdgcn_mfma_f32_16x16x32_bf16(ah1, bh1, acc[1][1], 0, 0, 0);
            acc[0][0] = __builtin_amdgcn_mfma_f32_16x16x32_bf16(ah0, bl0, acc[0][0], 0, 0, 0);
            acc[0][1] = __builtin_amdgcn_mfma_f32_16x16x32_bf16(ah0, bl1, acc[0][1], 0, 0, 0);
            acc[1][0] = __builtin_amdgcn_mfma_f32_16x16x32_bf16(ah1, bl0, acc[1][0], 0, 0, 0);
            acc[1][1] = __builtin_amdgcn_mfma_f32_16x16x32_bf16(ah1, bl1, acc[1][1], 0, 0, 0);
            acc[0][0] = __builtin_amdgcn_mfma_f32_16x16x32_bf16(al0, bh0, acc[0][0], 0, 0, 0);
            acc[0][1] = __builtin_amdgcn_mfma_f32_16x16x32_bf16(al0, bh1, acc[0][1], 0, 0, 0);
            acc[1][0] = __builtin_amdgcn_mfma_f32_16x16x32_bf16(al1, bh0, acc[1][0], 0, 0, 0);
            acc[1][1] = __builtin_amdgcn_mfma_f32_16x16x32_bf16(al1, bh1, acc[1][1], 0, 0, 0);
        }
    }

    __syncthreads();   // smem reused by epilogue
    const int region = row0 >> 7;   // 0=Q, 1=K, 2=V
    if (region == 2) {
        float (*LdsF)[68] = (float(*)[68])smem;
#pragma unroll
        for (int i = 0; i < 2; ++i)
#pragma unroll
            for (int j = 0; j < 2; ++j) {
                const int m = msub0 + i * 16 + quad * 4;
                const int n = nsub0 + j * 16 + l16;
#pragma unroll
                for (int r = 0; r < 4; ++r) LdsF[m + r][n] = acc[i][j][r];
            }
        __syncthreads();
        const int m = t >> 2, nb2 = (t & 3) * 16;
        const int vrow = b * 128 + (row0 - 256) + m;
        unsigned pk[8];
#pragma unroll
        for (int q = 0; q < 8; ++q)
            pk[q] = pack_rnd(LdsF[m][nb2 + 2 * q], LdsF[m][nb2 + 2 * q + 1]);
        unsigned short* dst = Vp + (size_t)vrow * N + col0 + nb2;
        *(uint4*)&dst[0] = *(uint4*)&pk[0];
        *(uint4*)&dst[8] = *(uint4*)&pk[4];
    } else {
        unsigned short (*LdsT)[68] = (unsigned short(*)[68])smem;
        const float sc = region ? 1.0f
                                : (0.17677669529663687f * 1.4426950408889634f);
#pragma unroll
        for (int i = 0; i < 2; ++i)
#pragma unroll
            for (int j = 0; j < 2; ++j) {
                const int m = msub0 + i * 16 + quad * 4;
                const int n = nsub0 + j * 16 + l16;
                uint2 pr;
                pr.x = pack_rnd(acc[i][j][0] * sc, acc[i][j][1] * sc);
                pr.y = pack_rnd(acc[i][j][2] * sc, acc[i][j][3] * sc);
                *(uint2*)&LdsT[n][m] = pr;
            }
        __syncthreads();
        const int n = t & 63, hb = (t >> 6) & 1, dh = t >> 7;
        const int h = ((row0 & 127) >> 5) + hb;
        const int m0 = hb * 32 + dh * 16;
        unsigned tmp[8];
        *(uint2*)&tmp[0] = *(const uint2*)&LdsT[n][m0];
        *(uint2*)&tmp[2] = *(const uint2*)&LdsT[n][m0 + 4];
        *(uint2*)&tmp[4] = *(const uint2*)&LdsT[n][m0 + 8];
        *(uint2*)&tmp[6] = *(const uint2*)&LdsT[n][m0 + 12];
        unsigned short* dst = (region ? Kp : Qp) +
            ((size_t)(b * 4 + h) * N + col0 + n) * 32 + dh * 16;
        *(uint4*)&dst[0] = *(uint4*)&tmp[0];
        *(uint4*)&dst[8] = *(uint4*)&tmp[4];
    }
}

// ---------------------------------------------------------------------------
// MFMA flash attention, no key-split, fused normalize+transpose epilogue.
// Block = 64 queries (4 waves x 16 q), one (b,h); 64 key-tiles of 64.
// S^T = K·Q^T; p = exp2(s); P per-wave LDS round-trip; O^T = V·P^T;
// l = 1·P^T via MFMA.  Epilogue: O/l -> LDS transpose -> Ot[b][n][c]
// bf16 hi/lo (gemm2 B-operand layout).  Grid (64 i0, 16 bh).
// ---------------------------------------------------------------------------
__global__ __launch_bounds__(256) void attn_fused(
    const unsigned short* __restrict__ Qp,
    const unsigned short* __restrict__ Kp,
    const unsigned short* __restrict__ Vp,
    unsigned short* __restrict__ Oth, unsigned short* __restrict__ Otl)
{
    const int N = N_TOK;
    const int bh = blockIdx.y;
    const int b = bh >> 2, h = bh & 3;
    const int i0 = blockIdx.x * 64;
    const int t = threadIdx.x;
    const int wave = t >> 6, lane = t & 63;
    const int l16 = lane & 15, quad = lane >> 4;

    __shared__ __align__(16) char smem[18944];
    unsigned short* KsH = (unsigned short*)smem;              // [64][40]
    unsigned short* VsH = (unsigned short*)(smem + 5120);     // [32][72]
    unsigned short* PtW = (unsigned short*)(smem + 9728) + wave * 16 * 72;  // [16][72]
    float (*Of)[65] = (float(*)[65])(smem + 9728);            // epilogue reuse

    short8 ones;
#pragma unroll
    for (int e = 0; e < 8; ++e) ones[e] = (short)0x3F80;

    short8 qh = *(const short8*)(Qp +
        ((size_t)bh * N + i0 + wave * 16 + l16) * 32 + quad * 8);

    floatx4 o[2] = {};      // O^T halves: rows d = half*16+quad*4+r, col q=l16
    floatx4 lacc = {};

    const int skey = t >> 2, sdp = (t & 3) * 8;
    const unsigned short* kp = Kp + ((size_t)bh * N + skey) * 32 + sdp;
    const int svd = t >> 3, svp = (t & 7) * 8;
    const unsigned short* vp = Vp + ((size_t)bh * 32 + svd) * N + svp;

    short8 kreg = *(const short8*)kp;
    short8 vreg = *(const short8*)vp;

    for (int it = 0; it < 64; ++it) {
        __syncthreads();
        *(short8*)(KsH + skey * 40 + sdp) = kreg;
        *(short8*)(VsH + svd * 72 + svp) = vreg;
        __syncthreads();

        if (it + 1 < 64) {
            kp += 64 * 32; vp += 64;
            kreg = *(const short8*)kp;
            vreg = *(const short8*)vp;
        }

        short8 kh0 = *(const short8*)(KsH + ( 0 + l16) * 40 + quad * 8);
        short8 kh1 = *(const short8*)(KsH + (16 + l16) * 40 + quad * 8);
        short8 kh2 = *(const short8*)(KsH + (32 + l16) * 40 + quad * 8);
        short8 kh3 = *(const short8*)(KsH + (48 + l16) * 40 + quad * 8);

        const floatx4 z = {0.0f, 0.0f, 0.0f, 0.0f};
        floatx4 st[4];
        st[0] = __builtin_amdgcn_mfma_f32_16x16x32_bf16(kh0, qh, z, 0, 0, 0);
        st[1] = __builtin_amdgcn_mfma_f32_16x16x32_bf16(kh1, qh, z, 0, 0, 0);
        st[2] = __builtin_amdgcn_mfma_f32_16x16x32_bf16(kh2, qh, z, 0, 0, 0);
        st[3] = __builtin_amdgcn_mfma_f32_16x16x32_bf16(kh3, qh, z, 0, 0, 0);

#pragma unroll
        for (int s = 0; s < 4; ++s) {
            float p0 = fast_exp2(st[s][0]);
            float p1 = fast_exp2(st[s][1]);
            float p2 = fast_exp2(st[s][2]);
            float p3 = fast_exp2(st[s][3]);
            uint2 pr;
            pr.x = pack_rnd(p0, p1);
            pr.y = pack_rnd(p2, p3);
            *(uint2*)(PtW + l16 * 72 + s * 16 + quad * 4) = pr;
        }

#pragma unroll
        for (int ks = 0; ks < 2; ++ks) {
            short8 pf  = *(const short8*)(PtW + l16 * 72 + ks * 32 + quad * 8);
            short8 vh0 = *(const short8*)(VsH + ( 0 + l16) * 72 + ks * 32 + quad * 8);
            short8 vh1 = *(const short8*)(VsH + (16 + l16) * 72 + ks * 32 + quad * 8);
            o[0] = __builtin_amdgcn_mfma_f32_16x16x32_bf16(vh0, pf, o[0], 0, 0, 0);
            o[1] = __builtin_amdgcn_mfma_f32_16x16x32_bf16(vh1, pf, o[1], 0, 0, 0);
            lacc = __builtin_amdgcn_mfma_f32_16x16x32_bf16(ones, pf, lacc, 0, 0, 0);
        }
    }

    // epilogue: normalize, transpose via LDS, emit bf16 hi/lo [n][c]
    const float inv = 1.0f / lacc[0];
    __syncthreads();   // all Pt/Vs reads done; smem reused as Of
#pragma unroll
    for (int half = 0; half < 2; ++half)
#pragma unroll
        for (int r = 0; r < 4; ++r)
            Of[half * 16 + quad * 4 + r][wave * 16 + l16] = o[half][r] * inv;
    __syncthreads();
    {
        const int q = t >> 2, db = (t & 3) * 8;
        unsigned ph[4], pl[4];
#pragma unroll
        for (int i = 0; i < 4; ++i)
            split_pack(Of[db + 2 * i][q], Of[db + 2 * i + 1][q], ph[i], pl[i]);
        const size_t off = ((size_t)b * N + i0 + q) * 128 + h * 32 + db;
        *(uint4*)(Oth + off) = *(uint4*)ph;
        *(uint4*)(Otl + off) = *(uint4*)pl;
    }
}

// ---------------------------------------------------------------------------
// Output GEMM, split-bf16 MFMA, LDS-staged B (coalesced), + bias.
// A = w_out hi/lo [m][128] direct global; B = Ot hi/lo [n][128] via LDS.
// Grid (64 n, 4 m, 4 b).
// ---------------------------------------------------------------------------
__global__ __launch_bounds__(256) void gemm2_fused(
    const unsigned short* __restrict__ Woh, const unsigned short* __restrict__ Wol,
    const unsigned short* __restrict__ Oth, const unsigned short* __restrict__ Otl,
    const float* __restrict__ bias, float* __restrict__ y)
{
    const int N = N_TOK;
    const int b = blockIdx.z;
    const int row0 = blockIdx.y * 64;
    const int col0 = blockIdx.x * 64;
    const int t = threadIdx.x;
    const int wave = t >> 6, lane = t & 63;
    const int l16 = lane & 15, quad = lane >> 4;
    const int msub0 = (wave & 1) * 32, nsub0 = (wave >> 1) * 32;

    __shared__ __align__(16) char smem[17408];
    unsigned short* BsH = (unsigned short*)smem;           // [64][40]
    unsigned short* BsL = (unsigned short*)(smem + 5120);  // [64][40]
    float (*LdsF)[68] = (float(*)[68])smem;                // epilogue reuse

    const unsigned short* aH = Woh + (size_t)(row0 + msub0 + l16) * 128 + quad * 8;
    const unsigned short* aL = Wol + (size_t)(row0 + msub0 + l16) * 128 + quad * 8;

    const int srow = t >> 2, sk = (t & 3) * 8;
    const unsigned short* gH = Oth + ((size_t)b * N + col0 + srow) * 128 + sk;
    const unsigned short* gL = Otl + ((size_t)b * N + col0 + srow) * 128 + sk;

    floatx4 acc[2][2] = {};
#pragma unroll
    for (int kc = 0; kc < 4; ++kc) {
        short8 hreg = *(const short8*)(gH + kc * 32);
        short8 lreg = *(const short8*)(gL + kc * 32);
        __syncthreads();
        *(short8*)(BsH + srow * 40 + sk) = hreg;
        *(short8*)(BsL + srow * 40 + sk) = lreg;
        __syncthreads();
        short8 bh0 = *(const short8*)(BsH + (nsub0 + l16) * 40 + quad * 8);
        short8 bh1 = *(const short8*)(BsH + (nsub0 + 16 + l16) * 40 + quad * 8);
        short8 bl0 = *(const short8*)(BsL + (nsub0 + l16) * 40 + quad * 8);
        short8 bl1 = *(const short8*)(BsL + (nsub0 + 16 + l16) * 40 + quad * 8);
        short8 ah0 = *(const short8*)(aH + kc * 32);
        short8 ah1 = *(const short8*)(aH + 16 * 128 + kc * 32);
        short8 al0 = *(const short8*)(aL + kc * 32);
        short8 al1 = *(const short8*)(aL + 16 * 128 + kc * 32);
        acc[0][0] = __builtin_amdgcn_mfma_f32_16x16x32_bf16(ah0, bh0, acc[0][0], 0, 0, 0);
        acc[0][1] = __builtin_amdgcn_mfma_f32_16x16x32_bf16(ah0, bh1, acc[0][1], 0, 0, 0);
        acc[1][0] = __builtin_amdgcn_mfma_f32_16x16x32_bf16(ah1, bh0, acc[1][0], 0, 0, 0);
        acc[1][1] = __builtin_amdgcn_mfma_f32_16x16x32_bf16(ah1, bh1, acc[1][1], 0, 0, 0);
        acc[0][0] = __builtin_amdgcn_mfma_f32_16x16x32_bf16(ah0, bl0, acc[0][0], 0, 0, 0);
        acc[0][1] = __builtin_amdgcn_mfma_f32_16x16x32_bf16(ah0, bl1, acc[0][1], 0, 0, 0);
        acc[1][0] = __builtin_amdgcn_mfma_f32_16x16x32_bf16(ah1, bl0, acc[1][0], 0, 0, 0);
        acc[1][1] = __builtin_amdgcn_mfma_f32_16x16x32_bf16(ah1, bl1, acc[1][1], 0, 0, 0);
        acc[0][0] = __builtin_amdgcn_mfma_f32_16x16x32_bf16(al0, bh0, acc[0][0], 0, 0, 0);
        acc[0][1] = __builtin_amdgcn_mfma_f32_16x16x32_bf16(al0, bh1, acc[0][1], 0, 0, 0);
        acc[1][0] = __builtin_amdgcn_mfma_f32_16x16x32_bf16(al1, bh0, acc[1][0], 0, 0, 0);
        acc[1][1] = __builtin_amdgcn_mfma_f32_16x16x32_bf16(al1, bh1, acc[1][1], 0, 0, 0);
    }

    __syncthreads();
#pragma unroll
    for (int i = 0; i < 2; ++i)
#pragma unroll
        for (int j = 0; j < 2; ++j) {
            const int m = msub0 + i * 16 + quad * 4;
            const int n = nsub0 + j * 16 + l16;
#pragma unroll
            for (int r = 0; r < 4; ++r) LdsF[m + r][n] = acc[i][j][r];
        }
    __syncthreads();
    const int m = t >> 2, nb = (t & 3) * 16;
    const float bv = bias[row0 + m];
    float* dst = y + ((size_t)b * 256 + row0 + m) * N + col0 + nb;
#pragma unroll
    for (int g = 0; g < 4; ++g) {
        float4 o4;
        o4.x = LdsF[m][nb + g * 4 + 0] + bv;
        o4.y = LdsF[m][nb + g * 4 + 1] + bv;
        o4.z = LdsF[m][nb + g * 4 + 2] + bv;
        o4.w = LdsF[m][nb + g * 4 + 3] + bv;
        *(float4*)(dst + g * 4) = o4;
    }
}

extern "C" void kernel_launch(void* const* d_in, const int* in_sizes, int n_in,
                              void* d_out, int out_size, void* d_ws, size_t ws_size,
                              hipStream_t stream) {
    const float* x     = (const float*)d_in[0];
    const float* w_qkv = (const float*)d_in[1];
    const float* w_out = (const float*)d_in[2];
    const float* b_out = (const float*)d_in[3];
    float* y = (float*)d_out;

    // workspace ~21.5 MB, no overlays:
    char* base = (char*)d_ws;
    unsigned short* Qp  = (unsigned short*)base;                       // 4 MiB
    unsigned short* Kp  = Qp + (size_t)16 * N_TOK * 32;
    unsigned short* Vp  = Kp + (size_t)16 * N_TOK * 32;
    unsigned short* Oth = Vp + (size_t)16 * N_TOK * 32;                // 4 MiB
    unsigned short* Otl = Oth + (size_t)BATCH * N_TOK * 128;
    unsigned short* Wqh = Otl + (size_t)BATCH * N_TOK * 128;
    unsigned short* Wql = Wqh + 98304;
    unsigned short* Woh = Wql + 98304;
    unsigned short* Wol = Woh + 32768;

    dim3 blk(256);
    convert_w<<<dim3(128), blk, 0, stream>>>(w_qkv, w_out, Wqh, Wql, Woh, Wol);
    gemm1_fused<<<dim3(64, 6, BATCH), blk, 0, stream>>>(
        Wqh, Wql, x, Qp, Kp, Vp);
    attn_fused<<<dim3(64, 16), blk, 0, stream>>>(Qp, Kp, Vp, Oth, Otl);
    gemm2_fused<<<dim3(64, 4, BATCH), blk, 0, stream>>>(
        Woh, Wol, Oth, Otl, b_out, y);
}

// Round 9
// 184.807 us; speedup vs baseline: 1.3363x; 1.0678x over previous
//
#include <hip/hip_runtime.h>

#define N_TOK 4096
#define BATCH 4

typedef __attribute__((ext_vector_type(8))) short short8;
typedef __attribute__((ext_vector_type(4))) float floatx4;

// Pack two floats to packed bf16 pair (round-half-away): 3 VALU ops.
__device__ __forceinline__ unsigned pack_rnd(float a, float b) {
    unsigned ra = __float_as_uint(a) + 0x8000u;
    unsigned rb = __float_as_uint(b) + 0x8000u;
    return __builtin_amdgcn_perm(rb, ra, 0x07060302u);
}

// Split two floats into bf16 hi-pair and lo-pair.
__device__ __forceinline__ void split_pack(float a, float b,
                                           unsigned &ph, unsigned &pl) {
    unsigned ra = __float_as_uint(a) + 0x8000u;
    unsigned rb = __float_as_uint(b) + 0x8000u;
    ph = __builtin_amdgcn_perm(rb, ra, 0x07060302u);
    float la = a - __uint_as_float(ra & 0xffff0000u);
    float lb = b - __uint_as_float(rb & 0xffff0000u);
    pl = __builtin_amdgcn_perm(__float_as_uint(lb) + 0x8000u,
                               __float_as_uint(la) + 0x8000u, 0x07060302u);
}

__device__ __forceinline__ short8 mk_short8(unsigned p0, unsigned p1,
                                            unsigned p2, unsigned p3) {
    union { unsigned u[4]; short8 s; } c;
    c.u[0] = p0; c.u[1] = p1; c.u[2] = p2; c.u[3] = p3;
    return c.s;
}

// Convert 8 consecutive fp32 (two float4) into hi/lo short8 fragments.
__device__ __forceinline__ void cvt_frag(const float* src,
                                         short8 &hi, short8 &lo) {
    float4 w0 = *(const float4*)src;
    float4 w1 = *(const float4*)(src + 4);
    unsigned ph[4], pl[4];
    split_pack(w0.x, w0.y, ph[0], pl[0]);
    split_pack(w0.z, w0.w, ph[1], pl[1]);
    split_pack(w1.x, w1.y, ph[2], pl[2]);
    split_pack(w1.z, w1.w, ph[3], pl[3]);
    hi = mk_short8(ph[0], ph[1], ph[2], ph[3]);
    lo = mk_short8(pl[0], pl[1], pl[2], pl[3]);
}

__device__ __forceinline__ float fast_exp2(float x) {
#if __has_builtin(__builtin_amdgcn_exp2f)
    return __builtin_amdgcn_exp2f(x);
#else
    return exp2f(x);
#endif
}

// ---------------------------------------------------------------------------
// QKV GEMM with fused x-conversion and inline W fp32->bf16 split (no
// convert_w kernel; W is L2-resident).  Per 64-k chunk: coalesced fp32 load
// of x[k][n] -> LDS, transpose+split to bf16 hi/lo [n][40-stride] LDS
// operands, 3-term split-bf16 MFMA.  Fused pack epilogue:
//   Q: Qp[bh][n][d] * (1/sqrt(32))*log2(e);  K: Kp[bh][n][d];  V: Vp[c][n].
// Grid (64 n, 6 m, 4 b), 256 threads.
// ---------------------------------------------------------------------------
__global__ __launch_bounds__(256) void gemm1_fused(
    const float* __restrict__ wq, const float* __restrict__ x,
    unsigned short* __restrict__ Qp, unsigned short* __restrict__ Kp,
    unsigned short* __restrict__ Vp)
{
    const int N = N_TOK;
    const int b = blockIdx.z;
    const int row0 = blockIdx.y * 64;
    const int col0 = blockIdx.x * 64;
    const int t = threadIdx.x;
    const int wave = t >> 6, lane = t & 63;
    const int l16 = lane & 15, quad = lane >> 4;
    const int msub0 = (wave & 1) * 32, nsub0 = (wave >> 1) * 32;

    __shared__ __align__(16) char smem[37888];
    float (*Xf)[68] = (float(*)[68])smem;                       // [64][68] fp32
    unsigned short* XsB = (unsigned short*)(smem + 17408);      // 4 x [64][40]

    const float* a0 = wq + (size_t)(row0 + msub0 + l16) * 256;
    const float* a1 = a0 + 16 * 256;

    floatx4 acc[2][2] = {};

    const int kr = t >> 2, nb = (t & 3) * 16;        // fp32 load role
    const int nr = t >> 2, kb = (t & 3) * 16;        // transpose role

    for (int kc = 0; kc < 4; ++kc) {
        __syncthreads();
        {
            const float* src = x + ((size_t)b * 256 + kc * 64 + kr) * N + col0 + nb;
#pragma unroll
            for (int j = 0; j < 4; ++j)
                *(float4*)&Xf[kr][nb + j * 4] = *(const float4*)(src + j * 4);
        }
        __syncthreads();
        {
            unsigned ph[8], pl[8];
#pragma unroll
            for (int q = 0; q < 8; ++q)
                split_pack(Xf[kb + 2 * q][nr], Xf[kb + 2 * q + 1][nr], ph[q], pl[q]);
            unsigned short* dH = XsB + (kb >> 5) * 5120 + nr * 40 + (kb & 31);
            unsigned short* dL = dH + 2560;
            *(uint4*)&dH[0] = *(uint4*)&ph[0];
            *(uint4*)&dH[8] = *(uint4*)&ph[4];
            *(uint4*)&dL[0] = *(uint4*)&pl[0];
            *(uint4*)&dL[8] = *(uint4*)&pl[4];
        }
        __syncthreads();
#pragma unroll
        for (int ks = 0; ks < 2; ++ks) {
            const unsigned short* bb = XsB + ks * 5120;
            short8 bh0 = *(const short8*)(bb + (nsub0 + l16) * 40 + quad * 8);
            short8 bh1 = *(const short8*)(bb + (nsub0 + 16 + l16) * 40 + quad * 8);
            short8 bl0 = *(const short8*)(bb + 2560 + (nsub0 + l16) * 40 + quad * 8);
            short8 bl1 = *(const short8*)(bb + 2560 + (nsub0 + 16 + l16) * 40 + quad * 8);
            const int kg = kc * 64 + ks * 32 + quad * 8;
            short8 ah0, al0, ah1, al1;
            cvt_frag(a0 + kg, ah0, al0);
            cvt_frag(a1 + kg, ah1, al1);
            acc[0][0] = __builtin_amdgcn_mfma_f32_16x16x32_bf16(ah0, bh0, acc[0][0], 0, 0, 0);
            acc[0][1] = __builtin_amdgcn_mfma_f32_16x16x32_bf16(ah0, bh1, acc[0][1], 0, 0, 0);
            acc[1][0] = __builtin_amdgcn_mfma_f32_16x16x32_bf16(ah1, bh0, acc[1][0], 0, 0, 0);
            acc[1][1] = __builtin_amdgcn_mfma_f32_16x16x32_bf16(ah1, bh1, acc[1][1], 0, 0, 0);
            acc[0][0] = __builtin_amdgcn_mfma_f32_16x16x32_bf16(ah0, bl0, acc[0][0], 0, 0, 0);
            acc[0][1] = __builtin_amdgcn_mfma_f32_16x16x32_bf16(ah0, bl1, acc[0][1], 0, 0, 0);
            acc[1][0] = __builtin_amdgcn_mfma_f32_16x16x32_bf16(ah1, bl0, acc[1][0], 0, 0, 0);
            acc[1][1] = __builtin_amdgcn_mfma_f32_16x16x32_bf16(ah1, bl1, acc[1][1], 0, 0, 0);
            acc[0][0] = __builtin_amdgcn_mfma_f32_16x16x32_bf16(al0, bh0, acc[0][0], 0, 0, 0);
            acc[0][1] = __builtin_amdgcn_mfma_f32_16x16x32_bf16(al0, bh1, acc[0][1], 0, 0, 0);
            acc[1][0] = __builtin_amdgcn_mfma_f32_16x16x32_bf16(al1, bh0, acc[1][0], 0, 0, 0);
            acc[1][1] = __builtin_amdgcn_mfma_f32_16x16x32_bf16(al1, bh1, acc[1][1], 0, 0, 0);
        }
    }

    __syncthreads();
    const int region = row0 >> 7;   // 0=Q, 1=K, 2=V
    if (region == 2) {
        float (*LdsF)[68] = (float(*)[68])smem;
#pragma unroll
        for (int i = 0; i < 2; ++i)
#pragma unroll
            for (int j = 0; j < 2; ++j) {
                const int m = msub0 + i * 16 + quad * 4;
                const int n = nsub0 + j * 16 + l16;
#pragma unroll
                for (int r = 0; r < 4; ++r) LdsF[m + r][n] = acc[i][j][r];
            }
        __syncthreads();
        const int m = t >> 2, nb2 = (t & 3) * 16;
        const int vrow = b * 128 + (row0 - 256) + m;
        unsigned pk[8];
#pragma unroll
        for (int q = 0; q < 8; ++q)
            pk[q] = pack_rnd(LdsF[m][nb2 + 2 * q], LdsF[m][nb2 + 2 * q + 1]);
        unsigned short* dst = Vp + (size_t)vrow * N + col0 + nb2;
        *(uint4*)&dst[0] = *(uint4*)&pk[0];
        *(uint4*)&dst[8] = *(uint4*)&pk[4];
    } else {
        unsigned short (*LdsT)[68] = (unsigned short(*)[68])smem;
        const float sc = region ? 1.0f
                                : (0.17677669529663687f * 1.4426950408889634f);
#pragma unroll
        for (int i = 0; i < 2; ++i)
#pragma unroll
            for (int j = 0; j < 2; ++j) {
                const int m = msub0 + i * 16 + quad * 4;
                const int n = nsub0 + j * 16 + l16;
                uint2 pr;
                pr.x = pack_rnd(acc[i][j][0] * sc, acc[i][j][1] * sc);
                pr.y = pack_rnd(acc[i][j][2] * sc, acc[i][j][3] * sc);
                *(uint2*)&LdsT[n][m] = pr;
            }
        __syncthreads();
        const int n = t & 63, hb = (t >> 6) & 1, dh = t >> 7;
        const int h = ((row0 & 127) >> 5) + hb;
        const int m0 = hb * 32 + dh * 16;
        unsigned tmp[8];
        *(uint2*)&tmp[0] = *(const uint2*)&LdsT[n][m0];
        *(uint2*)&tmp[2] = *(const uint2*)&LdsT[n][m0 + 4];
        *(uint2*)&tmp[4] = *(const uint2*)&LdsT[n][m0 + 8];
        *(uint2*)&tmp[6] = *(const uint2*)&LdsT[n][m0 + 12];
        unsigned short* dst = (region ? Kp : Qp) +
            ((size_t)(b * 4 + h) * N + col0 + n) * 32 + dh * 16;
        *(uint4*)&dst[0] = *(uint4*)&tmp[0];
        *(uint4*)&dst[8] = *(uint4*)&tmp[4];
    }
}

// ---------------------------------------------------------------------------
// MFMA flash attention, 512 threads = two 4-wave teams.  Block covers 128
// queries; team 0 handles keys 0..2047, team 1 keys 2048..4095 (32 tiles of
// 64 each).  Per-wave interior identical to R7 (32 q as 2 groups of 16:
// K-frags amortized over 8 QK MFMAs).  Teams combine O/l via LDS at the
// epilogue: normalize, transpose, bf16 hi/lo split -> Ot[b][n][c].
// Grid (32 i0, 16 bh).
// ---------------------------------------------------------------------------
__global__ __launch_bounds__(512) void attn_fused(
    const unsigned short* __restrict__ Qp,
    const unsigned short* __restrict__ Kp,
    const unsigned short* __restrict__ Vp,
    unsigned short* __restrict__ Oth, unsigned short* __restrict__ Otl)
{
    const int N = N_TOK;
    const int bh = blockIdx.y;
    const int b = bh >> 2, h = bh & 3;
    const int i0 = blockIdx.x * 128;
    const int t = threadIdx.x;
    const int wave = t >> 6, lane = t & 63;
    const int l16 = lane & 15, quad = lane >> 4;
    const int team = wave >> 2, w4 = wave & 3;

    __shared__ __align__(16) char smem[56320];
    unsigned short* Ks0 = (unsigned short*)smem;                 // [64][40]
    unsigned short* Ks1 = Ks0 + 2560;
    unsigned short* Vs0 = (unsigned short*)(smem + 10240);       // [32][72]
    unsigned short* Vs1 = Vs0 + 2304;
    unsigned short* PtW = (unsigned short*)(smem + 19456) + wave * 2304; // [32][72]

    const unsigned short* Ksr = team ? Ks1 : Ks0;
    const unsigned short* Vsr = team ? Vs1 : Vs0;

    short8 ones;
#pragma unroll
    for (int e = 0; e < 8; ++e) ones[e] = (short)0x3F80;

    short8 qh[2];
#pragma unroll
    for (int g = 0; g < 2; ++g)
        qh[g] = *(const short8*)(Qp +
            ((size_t)bh * N + i0 + w4 * 32 + g * 16 + l16) * 32 + quad * 8);

    floatx4 o[2][2] = {};
    floatx4 lacc[2] = {};

    // staging: threads 0..255 stage K for both teams, 256..511 stage V
    const int st_k = t & 255;
    const int skey = st_k >> 2, sdp = (st_k & 3) * 8;
    const int svd = st_k >> 3, svp = (st_k & 7) * 8;
    const unsigned short* kp0 = Kp + ((size_t)bh * N + skey) * 32 + sdp;
    const unsigned short* kp1 = kp0 + (size_t)2048 * 32;
    const unsigned short* vp0 = Vp + ((size_t)bh * 32 + svd) * N + svp;
    const unsigned short* vp1 = vp0 + 2048;

    short8 r0, r1;
    if (t < 256) { r0 = *(const short8*)kp0; r1 = *(const short8*)kp1; }
    else         { r0 = *(const short8*)vp0; r1 = *(const short8*)vp1; }

    for (int it = 0; it < 32; ++it) {
        __syncthreads();
        if (t < 256) {
            *(short8*)(Ks0 + skey * 40 + sdp) = r0;
            *(short8*)(Ks1 + skey * 40 + sdp) = r1;
        } else {
            *(short8*)(Vs0 + svd * 72 + svp) = r0;
            *(short8*)(Vs1 + svd * 72 + svp) = r1;
        }
        __syncthreads();

        if (it + 1 < 32) {
            kp0 += 64 * 32; kp1 += 64 * 32; vp0 += 64; vp1 += 64;
            if (t < 256) { r0 = *(const short8*)kp0; r1 = *(const short8*)kp1; }
            else         { r0 = *(const short8*)vp0; r1 = *(const short8*)vp1; }
        }

        short8 kh0 = *(const short8*)(Ksr + ( 0 + l16) * 40 + quad * 8);
        short8 kh1 = *(const short8*)(Ksr + (16 + l16) * 40 + quad * 8);
        short8 kh2 = *(const short8*)(Ksr + (32 + l16) * 40 + quad * 8);
        short8 kh3 = *(const short8*)(Ksr + (48 + l16) * 40 + quad * 8);

#pragma unroll
        for (int g = 0; g < 2; ++g) {
            const floatx4 z = {0.0f, 0.0f, 0.0f, 0.0f};
            floatx4 stv[4];
            stv[0] = __builtin_amdgcn_mfma_f32_16x16x32_bf16(kh0, qh[g], z, 0, 0, 0);
            stv[1] = __builtin_amdgcn_mfma_f32_16x16x32_bf16(kh1, qh[g], z, 0, 0, 0);
            stv[2] = __builtin_amdgcn_mfma_f32_16x16x32_bf16(kh2, qh[g], z, 0, 0, 0);
            stv[3] = __builtin_amdgcn_mfma_f32_16x16x32_bf16(kh3, qh[g], z, 0, 0, 0);
#pragma unroll
            for (int s = 0; s < 4; ++s) {
                float p0 = fast_exp2(stv[s][0]);
                float p1 = fast_exp2(stv[s][1]);
                float p2 = fast_exp2(stv[s][2]);
                float p3 = fast_exp2(stv[s][3]);
                uint2 pr;
                pr.x = pack_rnd(p0, p1);
                pr.y = pack_rnd(p2, p3);
                *(uint2*)(PtW + (g * 16 + l16) * 72 + s * 16 + quad * 4) = pr;
            }
        }

#pragma unroll
        for (int ks = 0; ks < 2; ++ks) {
            short8 pf0 = *(const short8*)(PtW + ( 0 + l16) * 72 + ks * 32 + quad * 8);
            short8 pf1 = *(const short8*)(PtW + (16 + l16) * 72 + ks * 32 + quad * 8);
            short8 vh0 = *(const short8*)(Vsr + ( 0 + l16) * 72 + ks * 32 + quad * 8);
            short8 vh1 = *(const short8*)(Vsr + (16 + l16) * 72 + ks * 32 + quad * 8);
            o[0][0] = __builtin_amdgcn_mfma_f32_16x16x32_bf16(vh0, pf0, o[0][0], 0, 0, 0);
            o[0][1] = __builtin_amdgcn_mfma_f32_16x16x32_bf16(vh1, pf0, o[0][1], 0, 0, 0);
            o[1][0] = __builtin_amdgcn_mfma_f32_16x16x32_bf16(vh0, pf1, o[1][0], 0, 0, 0);
            o[1][1] = __builtin_amdgcn_mfma_f32_16x16x32_bf16(vh1, pf1, o[1][1], 0, 0, 0);
            lacc[0] = __builtin_amdgcn_mfma_f32_16x16x32_bf16(ones, pf0, lacc[0], 0, 0, 0);
            lacc[1] = __builtin_amdgcn_mfma_f32_16x16x32_bf16(ones, pf1, lacc[1], 0, 0, 0);
        }
    }

    // ---- epilogue: cross-team combine, normalize, transpose, split ----
    __syncthreads();
    float (*OfB)[132] = (float(*)[132])smem;                 // [32][132] team1 O^T
    float* Lb = (float*)(smem + 16896);                      // [128] team1 l
    float (*OfA)[132] = (float(*)[132])(smem + 17408);       // [32][132] final

    if (team == 1) {
#pragma unroll
        for (int g = 0; g < 2; ++g) {
            const int q = w4 * 32 + g * 16 + l16;
#pragma unroll
            for (int half = 0; half < 2; ++half)
#pragma unroll
                for (int r = 0; r < 4; ++r)
                    OfB[half * 16 + quad * 4 + r][q] = o[g][half][r];
            if (quad == 0) Lb[q] = lacc[g][0];
        }
    }
    __syncthreads();
    if (team == 0) {
#pragma unroll
        for (int g = 0; g < 2; ++g) {
            const int q = w4 * 32 + g * 16 + l16;
            const float inv = 1.0f / (lacc[g][0] + Lb[q]);
#pragma unroll
            for (int half = 0; half < 2; ++half)
#pragma unroll
                for (int r = 0; r < 4; ++r) {
                    const int d = half * 16 + quad * 4 + r;
                    OfA[d][q] = (o[g][half][r] + OfB[d][q]) * inv;
                }
        }
    }
    __syncthreads();
    {
        const int q = t >> 2, db = (t & 3) * 8;
        unsigned ph[4], pl[4];
#pragma unroll
        for (int i = 0; i < 4; ++i)
            split_pack(OfA[db + 2 * i][q], OfA[db + 2 * i + 1][q], ph[i], pl[i]);
        const size_t off = ((size_t)b * N + i0 + q) * 128 + h * 32 + db;
        *(uint4*)(Oth + off) = *(uint4*)ph;
        *(uint4*)(Otl + off) = *(uint4*)pl;
    }
}

// ---------------------------------------------------------------------------
// Output GEMM, split-bf16 MFMA, LDS-staged B, inline-converted W (preloaded),
// + bias.  Grid (64 n, 4 m, 4 b), 256 threads.
// ---------------------------------------------------------------------------
__global__ __launch_bounds__(256) void gemm2_fused(
    const float* __restrict__ wo,
    const unsigned short* __restrict__ Oth, const unsigned short* __restrict__ Otl,
    const float* __restrict__ bias, float* __restrict__ y)
{
    const int N = N_TOK;
    const int b = blockIdx.z;
    const int row0 = blockIdx.y * 64;
    const int col0 = blockIdx.x * 64;
    const int t = threadIdx.x;
    const int wave = t >> 6, lane = t & 63;
    const int l16 = lane & 15, quad = lane >> 4;
    const int msub0 = (wave & 1) * 32, nsub0 = (wave >> 1) * 32;

    __shared__ __align__(16) char smem[17408];
    unsigned short* BsH = (unsigned short*)smem;           // [64][40]
    unsigned short* BsL = (unsigned short*)(smem + 5120);  // [64][40]
    float (*LdsF)[68] = (float(*)[68])smem;                // epilogue reuse

    // preload + convert A fragments (w_out fp32 -> bf16 hi/lo)
    short8 ah[4][2], al[4][2];
#pragma unroll
    for (int kc = 0; kc < 4; ++kc)
#pragma unroll
        for (int r = 0; r < 2; ++r)
            cvt_frag(wo + (size_t)(row0 + msub0 + r * 16 + l16) * 128 +
                         kc * 32 + quad * 8,
                     ah[kc][r], al[kc][r]);

    const int srow = t >> 2, sk = (t & 3) * 8;
    const unsigned short* gH = Oth + ((size_t)b * N + col0 + srow) * 128 + sk;
    const unsigned short* gL = Otl + ((size_t)b * N + col0 + srow) * 128 + sk;

    floatx4 acc[2][2] = {};
#pragma unroll
    for (int kc = 0; kc < 4; ++kc) {
        short8 hreg = *(const short8*)(gH + kc * 32);
        short8 lreg = *(const short8*)(gL + kc * 32);
        __syncthreads();
        *(short8*)(BsH + srow * 40 + sk) = hreg;
        *(short8*)(BsL + srow * 40 + sk) = lreg;
        __syncthreads();
        short8 bh0 = *(const short8*)(BsH + (nsub0 + l16) * 40 + quad * 8);
        short8 bh1 = *(const short8*)(BsH + (nsub0 + 16 + l16) * 40 + quad * 8);
        short8 bl0 = *(const short8*)(BsL + (nsub0 + l16) * 40 + quad * 8);
        short8 bl1 = *(const short8*)(BsL + (nsub0 + 16 + l16) * 40 + quad * 8);
        acc[0][0] = __builtin_amdgcn_mfma_f32_16x16x32_bf16(ah[kc][0], bh0, acc[0][0], 0, 0, 0);
        acc[0][1] = __builtin_amdgcn_mfma_f32_16x16x32_bf16(ah[kc][0], bh1, acc[0][1], 0, 0, 0);
        acc[1][0] = __builtin_amdgcn_mfma_f32_16x16x32_bf16(ah[kc][1], bh0, acc[1][0], 0, 0, 0);
        acc[1][1] = __builtin_amdgcn_mfma_f32_16x16x32_bf16(ah[kc][1], bh1, acc[1][1], 0, 0, 0);
        acc[0][0] = __builtin_amdgcn_mfma_f32_16x16x32_bf16(ah[kc][0], bl0, acc[0][0], 0, 0, 0);
        acc[0][1] = __builtin_amdgcn_mfma_f32_16x16x32_bf16(ah[kc][0], bl1, acc[0][1], 0, 0, 0);
        acc[1][0] = __builtin_amdgcn_mfma_f32_16x16x32_bf16(ah[kc][1], bl0, acc[1][0], 0, 0, 0);
        acc[1][1] = __builtin_amdgcn_mfma_f32_16x16x32_bf16(ah[kc][1], bl1, acc[1][1], 0, 0, 0);
        acc[0][0] = __builtin_amdgcn_mfma_f32_16x16x32_bf16(al[kc][0], bh0, acc[0][0], 0, 0, 0);
        acc[0][1] = __builtin_amdgcn_mfma_f32_16x16x32_bf16(al[kc][0], bh1, acc[0][1], 0, 0, 0);
        acc[1][0] = __builtin_amdgcn_mfma_f32_16x16x32_bf16(al[kc][1], bh0, acc[1][0], 0, 0, 0);
        acc[1][1] = __builtin_amdgcn_mfma_f32_16x16x32_bf16(al[kc][1], bh1, acc[1][1], 0, 0, 0);
    }

    __syncthreads();
#pragma unroll
    for (int i = 0; i < 2; ++i)
#pragma unroll
        for (int j = 0; j < 2; ++j) {
            const int m = msub0 + i * 16 + quad * 4;
            const int n = nsub0 + j * 16 + l16;
#pragma unroll
            for (int r = 0; r < 4; ++r) LdsF[m + r][n] = acc[i][j][r];
        }
    __syncthreads();
    const int m = t >> 2, nb = (t & 3) * 16;
    const float bv = bias[row0 + m];
    float* dst = y + ((size_t)b * 256 + row0 + m) * N + col0 + nb;
#pragma unroll
    for (int g = 0; g < 4; ++g) {
        float4 o4;
        o4.x = LdsF[m][nb + g * 4 + 0] + bv;
        o4.y = LdsF[m][nb + g * 4 + 1] + bv;
        o4.z = LdsF[m][nb + g * 4 + 2] + bv;
        o4.w = LdsF[m][nb + g * 4 + 3] + bv;
        *(float4*)(dst + g * 4) = o4;
    }
}

extern "C" void kernel_launch(void* const* d_in, const int* in_sizes, int n_in,
                              void* d_out, int out_size, void* d_ws, size_t ws_size,
                              hipStream_t stream) {
    const float* x     = (const float*)d_in[0];
    const float* w_qkv = (const float*)d_in[1];
    const float* w_out = (const float*)d_in[2];
    const float* b_out = (const float*)d_in[3];
    float* y = (float*)d_out;

    // workspace 20 MiB: Qp, Kp, Vp, Oth, Otl (4 MiB each)
    char* base = (char*)d_ws;
    unsigned short* Qp  = (unsigned short*)base;
    unsigned short* Kp  = Qp + (size_t)16 * N_TOK * 32;
    unsigned short* Vp  = Kp + (size_t)16 * N_TOK * 32;
    unsigned short* Oth = Vp + (size_t)16 * N_TOK * 32;
    unsigned short* Otl = Oth + (size_t)BATCH * N_TOK * 128;

    gemm1_fused<<<dim3(64, 6, BATCH), dim3(256), 0, stream>>>(
        w_qkv, x, Qp, Kp, Vp);
    attn_fused<<<dim3(32, 16), dim3(512), 0, stream>>>(Qp, Kp, Vp, Oth, Otl);
    gemm2_fused<<<dim3(64, 4, BATCH), dim3(256), 0, stream>>>(
        w_out, Oth, Otl, b_out, y);
}

// Round 10
// 167.968 us; speedup vs baseline: 1.4703x; 1.1003x over previous
//
#include <hip/hip_runtime.h>

#define N_TOK 4096
#define BATCH 4

typedef __attribute__((ext_vector_type(8))) short short8;
typedef __attribute__((ext_vector_type(4))) float floatx4;

// Pack two floats to packed bf16 pair (round-half-away): 3 VALU ops.
__device__ __forceinline__ unsigned pack_rnd(float a, float b) {
    unsigned ra = __float_as_uint(a) + 0x8000u;
    unsigned rb = __float_as_uint(b) + 0x8000u;
    return __builtin_amdgcn_perm(rb, ra, 0x07060302u);
}

// Split two floats into bf16 hi-pair and lo-pair.
__device__ __forceinline__ void split_pack(float a, float b,
                                           unsigned &ph, unsigned &pl) {
    unsigned ra = __float_as_uint(a) + 0x8000u;
    unsigned rb = __float_as_uint(b) + 0x8000u;
    ph = __builtin_amdgcn_perm(rb, ra, 0x07060302u);
    float la = a - __uint_as_float(ra & 0xffff0000u);
    float lb = b - __uint_as_float(rb & 0xffff0000u);
    pl = __builtin_amdgcn_perm(__float_as_uint(lb) + 0x8000u,
                               __float_as_uint(la) + 0x8000u, 0x07060302u);
}

__device__ __forceinline__ short8 mk_short8(unsigned p0, unsigned p1,
                                            unsigned p2, unsigned p3) {
    union { unsigned u[4]; short8 s; } c;
    c.u[0] = p0; c.u[1] = p1; c.u[2] = p2; c.u[3] = p3;
    return c.s;
}

// Convert 8 consecutive fp32 (two float4) into hi/lo short8 fragments.
__device__ __forceinline__ void cvt_frag(const float* src,
                                         short8 &hi, short8 &lo) {
    float4 w0 = *(const float4*)src;
    float4 w1 = *(const float4*)(src + 4);
    unsigned ph[4], pl[4];
    split_pack(w0.x, w0.y, ph[0], pl[0]);
    split_pack(w0.z, w0.w, ph[1], pl[1]);
    split_pack(w1.x, w1.y, ph[2], pl[2]);
    split_pack(w1.z, w1.w, ph[3], pl[3]);
    hi = mk_short8(ph[0], ph[1], ph[2], ph[3]);
    lo = mk_short8(pl[0], pl[1], pl[2], pl[3]);
}

__device__ __forceinline__ float fast_exp2(float x) {
#if __has_builtin(__builtin_amdgcn_exp2f)
    return __builtin_amdgcn_exp2f(x);
#else
    return exp2f(x);
#endif
}

// ---------------------------------------------------------------------------
// QKV GEMM, fully LDS-staged operands.  Per 32-k chunk:
//   W: coalesced fp32 load (4 lanes x 128B per row), in-register bf16 hi/lo
//      split, staged to LDS [m][40] -- shared by all 4 waves.
//   x: coalesced fp32 load -> LDS [32][68], transpose+split -> [n][40] hi/lo.
//   12 MFMAs (3-term split-bf16), all operands via ds_read_b128.
// Fused pack epilogue: Q (scaled), K transposed to [bh][n][d]; V to [c][n].
// Grid (64 n, 6 m, 4 b), 256 threads.  LDS 28.5 KB -> 5 blocks/CU.
// ---------------------------------------------------------------------------
__global__ __launch_bounds__(256) void gemm1_fused(
    const float* __restrict__ wq, const float* __restrict__ x,
    unsigned short* __restrict__ Qp, unsigned short* __restrict__ Kp,
    unsigned short* __restrict__ Vp)
{
    const int N = N_TOK;
    const int b = blockIdx.z;
    const int row0 = blockIdx.y * 64;
    const int col0 = blockIdx.x * 64;
    const int t = threadIdx.x;
    const int wave = t >> 6, lane = t & 63;
    const int l16 = lane & 15, quad = lane >> 4;
    const int msub0 = (wave & 1) * 32, nsub0 = (wave >> 1) * 32;

    __shared__ __align__(16) char smem[29184];
    float (*Xf)[68] = (float(*)[68])smem;                      // [32][68] 8704B
    unsigned short* XsH = (unsigned short*)(smem + 8704);      // [64][40]
    unsigned short* XsL = (unsigned short*)(smem + 13824);
    unsigned short* WsH = (unsigned short*)(smem + 18944);
    unsigned short* WsL = (unsigned short*)(smem + 24064);

    floatx4 acc[2][2] = {};

    const int xr = t >> 3, xnb = (t & 7) * 8;      // x load role
    const int tnr = t >> 2, tkb = (t & 3) * 8;     // x transpose role
    const int wm = t >> 2, wk = (t & 3) * 8;       // W load/convert role

    for (int kc = 0; kc < 8; ++kc) {
        __syncthreads();
        {   // W chunk: coalesced load + in-reg split -> LDS [m][40] hi/lo
            const float* wsrc = wq + (size_t)(row0 + wm) * 256 + kc * 32 + wk;
            float4 w0 = *(const float4*)wsrc;
            float4 w1 = *(const float4*)(wsrc + 4);
            unsigned ph[4], pl[4];
            split_pack(w0.x, w0.y, ph[0], pl[0]);
            split_pack(w0.z, w0.w, ph[1], pl[1]);
            split_pack(w1.x, w1.y, ph[2], pl[2]);
            split_pack(w1.z, w1.w, ph[3], pl[3]);
            *(uint4*)(WsH + wm * 40 + wk) = *(uint4*)ph;
            *(uint4*)(WsL + wm * 40 + wk) = *(uint4*)pl;
        }
        {   // x chunk: coalesced fp32 -> Xf
            const float* src = x + ((size_t)b * 256 + kc * 32 + xr) * N + col0 + xnb;
            *(float4*)&Xf[xr][xnb]     = *(const float4*)src;
            *(float4*)&Xf[xr][xnb + 4] = *(const float4*)(src + 4);
        }
        __syncthreads();
        {   // transpose+split x -> [n][40] hi/lo
            unsigned ph[4], pl[4];
#pragma unroll
            for (int q = 0; q < 4; ++q)
                split_pack(Xf[tkb + 2 * q][tnr], Xf[tkb + 2 * q + 1][tnr],
                           ph[q], pl[q]);
            *(uint4*)(XsH + tnr * 40 + tkb) = *(uint4*)ph;
            *(uint4*)(XsL + tnr * 40 + tkb) = *(uint4*)pl;
        }
        __syncthreads();
        short8 ah0 = *(const short8*)(WsH + (msub0 + l16) * 40 + quad * 8);
        short8 ah1 = *(const short8*)(WsH + (msub0 + 16 + l16) * 40 + quad * 8);
        short8 al0 = *(const short8*)(WsL + (msub0 + l16) * 40 + quad * 8);
        short8 al1 = *(const short8*)(WsL + (msub0 + 16 + l16) * 40 + quad * 8);
        short8 bh0 = *(const short8*)(XsH + (nsub0 + l16) * 40 + quad * 8);
        short8 bh1 = *(const short8*)(XsH + (nsub0 + 16 + l16) * 40 + quad * 8);
        short8 bl0 = *(const short8*)(XsL + (nsub0 + l16) * 40 + quad * 8);
        short8 bl1 = *(const short8*)(XsL + (nsub0 + 16 + l16) * 40 + quad * 8);
        acc[0][0] = __builtin_amdgcn_mfma_f32_16x16x32_bf16(ah0, bh0, acc[0][0], 0, 0, 0);
        acc[0][1] = __builtin_amdgcn_mfma_f32_16x16x32_bf16(ah0, bh1, acc[0][1], 0, 0, 0);
        acc[1][0] = __builtin_amdgcn_mfma_f32_16x16x32_bf16(ah1, bh0, acc[1][0], 0, 0, 0);
        acc[1][1] = __builtin_amdgcn_mfma_f32_16x16x32_bf16(ah1, bh1, acc[1][1], 0, 0, 0);
        acc[0][0] = __builtin_amdgcn_mfma_f32_16x16x32_bf16(ah0, bl0, acc[0][0], 0, 0, 0);
        acc[0][1] = __builtin_amdgcn_mfma_f32_16x16x32_bf16(ah0, bl1, acc[0][1], 0, 0, 0);
        acc[1][0] = __builtin_amdgcn_mfma_f32_16x16x32_bf16(ah1, bl0, acc[1][0], 0, 0, 0);
        acc[1][1] = __builtin_amdgcn_mfma_f32_16x16x32_bf16(ah1, bl1, acc[1][1], 0, 0, 0);
        acc[0][0] = __builtin_amdgcn_mfma_f32_16x16x32_bf16(al0, bh0, acc[0][0], 0, 0, 0);
        acc[0][1] = __builtin_amdgcn_mfma_f32_16x16x32_bf16(al0, bh1, acc[0][1], 0, 0, 0);
        acc[1][0] = __builtin_amdgcn_mfma_f32_16x16x32_bf16(al1, bh0, acc[1][0], 0, 0, 0);
        acc[1][1] = __builtin_amdgcn_mfma_f32_16x16x32_bf16(al1, bh1, acc[1][1], 0, 0, 0);
    }

    __syncthreads();
    const int region = row0 >> 7;   // 0=Q, 1=K, 2=V
    if (region == 2) {
        float (*LdsF)[68] = (float(*)[68])smem;
#pragma unroll
        for (int i = 0; i < 2; ++i)
#pragma unroll
            for (int j = 0; j < 2; ++j) {
                const int m = msub0 + i * 16 + quad * 4;
                const int n = nsub0 + j * 16 + l16;
#pragma unroll
                for (int r = 0; r < 4; ++r) LdsF[m + r][n] = acc[i][j][r];
            }
        __syncthreads();
        const int m = t >> 2, nb2 = (t & 3) * 16;
        const int vrow = b * 128 + (row0 - 256) + m;
        unsigned pk[8];
#pragma unroll
        for (int q = 0; q < 8; ++q)
            pk[q] = pack_rnd(LdsF[m][nb2 + 2 * q], LdsF[m][nb2 + 2 * q + 1]);
        unsigned short* dst = Vp + (size_t)vrow * N + col0 + nb2;
        *(uint4*)&dst[0] = *(uint4*)&pk[0];
        *(uint4*)&dst[8] = *(uint4*)&pk[4];
    } else {
        unsigned short (*LdsT)[68] = (unsigned short(*)[68])smem;
        const float sc = region ? 1.0f
                                : (0.17677669529663687f * 1.4426950408889634f);
#pragma unroll
        for (int i = 0; i < 2; ++i)
#pragma unroll
            for (int j = 0; j < 2; ++j) {
                const int m = msub0 + i * 16 + quad * 4;
                const int n = nsub0 + j * 16 + l16;
                uint2 pr;
                pr.x = pack_rnd(acc[i][j][0] * sc, acc[i][j][1] * sc);
                pr.y = pack_rnd(acc[i][j][2] * sc, acc[i][j][3] * sc);
                *(uint2*)&LdsT[n][m] = pr;
            }
        __syncthreads();
        const int n = t & 63, hb = (t >> 6) & 1, dh = t >> 7;
        const int h = ((row0 & 127) >> 5) + hb;
        const int m0 = hb * 32 + dh * 16;
        unsigned tmp[8];
        *(uint2*)&tmp[0] = *(const uint2*)&LdsT[n][m0];
        *(uint2*)&tmp[2] = *(const uint2*)&LdsT[n][m0 + 4];
        *(uint2*)&tmp[4] = *(const uint2*)&LdsT[n][m0 + 8];
        *(uint2*)&tmp[6] = *(const uint2*)&LdsT[n][m0 + 12];
        unsigned short* dst = (region ? Kp : Qp) +
            ((size_t)(b * 4 + h) * N + col0 + n) * 32 + dh * 16;
        *(uint4*)&dst[0] = *(uint4*)&tmp[0];
        *(uint4*)&dst[8] = *(uint4*)&tmp[4];
    }
}

// ---------------------------------------------------------------------------
// MFMA flash attention, 512 threads = two 4-wave teams, double-buffered K/V
// staging (ONE barrier per key-tile: stage writes to buf[1-cur] overlap
// compute reads of buf[cur]).  Per-wave interior identical to R9.
// Epilogue: cross-team combine, normalize, transpose, bf16 hi/lo split.
// Grid (32 i0, 16 bh).  LDS 74 KB -> 2 blocks/CU.
// ---------------------------------------------------------------------------
__global__ __launch_bounds__(512) void attn_fused(
    const unsigned short* __restrict__ Qp,
    const unsigned short* __restrict__ Kp,
    const unsigned short* __restrict__ Vp,
    unsigned short* __restrict__ Oth, unsigned short* __restrict__ Otl)
{
    const int N = N_TOK;
    const int bh = blockIdx.y;
    const int b = bh >> 2, h = bh & 3;
    const int i0 = blockIdx.x * 128;
    const int t = threadIdx.x;
    const int wave = t >> 6, lane = t & 63;
    const int l16 = lane & 15, quad = lane >> 4;
    const int team = wave >> 2, w4 = wave & 3;

    // shorts: K bufs [2][2 team][64][40] @0..10239; V bufs [2][2][32][72]
    // @10240..19455; Pt 8 x [32][72] @19456..37887.  75776 bytes total.
    __shared__ __align__(16) char smem[75776];
    unsigned short* S = (unsigned short*)smem;
    unsigned short* PtW = S + 19456 + wave * 2304;

    short8 ones;
#pragma unroll
    for (int e = 0; e < 8; ++e) ones[e] = (short)0x3F80;

    short8 qh[2];
#pragma unroll
    for (int g = 0; g < 2; ++g)
        qh[g] = *(const short8*)(Qp +
            ((size_t)bh * N + i0 + w4 * 32 + g * 16 + l16) * 32 + quad * 8);

    floatx4 o[2][2] = {};
    floatx4 lacc[2] = {};

    // staging: threads 0..255 stage K (both teams), 256..511 stage V
    const int st_k = t & 255;
    const int skey = st_k >> 2, sdp = (st_k & 3) * 8;
    const int svd = st_k >> 3, svp = (st_k & 7) * 8;
    const unsigned short* kp0 = Kp + ((size_t)bh * N + skey) * 32 + sdp;
    const unsigned short* kp1 = kp0 + (size_t)2048 * 32;
    const unsigned short* vp0 = Vp + ((size_t)bh * 32 + svd) * N + svp;
    const unsigned short* vp1 = vp0 + 2048;

    short8 r0, r1;
    if (t < 256) { r0 = *(const short8*)kp0; r1 = *(const short8*)kp1; }
    else         { r0 = *(const short8*)vp0; r1 = *(const short8*)vp1; }
    // store tile 0 -> buf 0
    if (t < 256) {
        *(short8*)(S + skey * 40 + sdp) = r0;
        *(short8*)(S + 2560 + skey * 40 + sdp) = r1;
    } else {
        *(short8*)(S + 10240 + svd * 72 + svp) = r0;
        *(short8*)(S + 10240 + 2304 + svd * 72 + svp) = r1;
    }
    // prefetch tile 1 into regs
    kp0 += 64 * 32; kp1 += 64 * 32; vp0 += 64; vp1 += 64;
    if (t < 256) { r0 = *(const short8*)kp0; r1 = *(const short8*)kp1; }
    else         { r0 = *(const short8*)vp0; r1 = *(const short8*)vp1; }
    __syncthreads();

    for (int it = 0; it < 32; ++it) {
        const int cur = it & 1;
        // stage tile it+1 into the other buffer (overlaps compute of cur)
        if (it + 1 < 32) {
            const int nb = 1 - cur;
            if (t < 256) {
                *(short8*)(S + nb * 5120 + skey * 40 + sdp) = r0;
                *(short8*)(S + nb * 5120 + 2560 + skey * 40 + sdp) = r1;
            } else {
                *(short8*)(S + 10240 + nb * 4608 + svd * 72 + svp) = r0;
                *(short8*)(S + 10240 + nb * 4608 + 2304 + svd * 72 + svp) = r1;
            }
        }
        // prefetch tile it+2 into regs
        if (it + 2 < 32) {
            kp0 += 64 * 32; kp1 += 64 * 32; vp0 += 64; vp1 += 64;
            if (t < 256) { r0 = *(const short8*)kp0; r1 = *(const short8*)kp1; }
            else         { r0 = *(const short8*)vp0; r1 = *(const short8*)vp1; }
        }

        const unsigned short* Ksr = S + cur * 5120 + team * 2560;
        const unsigned short* Vsr = S + 10240 + cur * 4608 + team * 2304;

        short8 kh0 = *(const short8*)(Ksr + ( 0 + l16) * 40 + quad * 8);
        short8 kh1 = *(const short8*)(Ksr + (16 + l16) * 40 + quad * 8);
        short8 kh2 = *(const short8*)(Ksr + (32 + l16) * 40 + quad * 8);
        short8 kh3 = *(const short8*)(Ksr + (48 + l16) * 40 + quad * 8);

#pragma unroll
        for (int g = 0; g < 2; ++g) {
            const floatx4 z = {0.0f, 0.0f, 0.0f, 0.0f};
            floatx4 stv[4];
            stv[0] = __builtin_amdgcn_mfma_f32_16x16x32_bf16(kh0, qh[g], z, 0, 0, 0);
            stv[1] = __builtin_amdgcn_mfma_f32_16x16x32_bf16(kh1, qh[g], z, 0, 0, 0);
            stv[2] = __builtin_amdgcn_mfma_f32_16x16x32_bf16(kh2, qh[g], z, 0, 0, 0);
            stv[3] = __builtin_amdgcn_mfma_f32_16x16x32_bf16(kh3, qh[g], z, 0, 0, 0);
#pragma unroll
            for (int s = 0; s < 4; ++s) {
                float p0 = fast_exp2(stv[s][0]);
                float p1 = fast_exp2(stv[s][1]);
                float p2 = fast_exp2(stv[s][2]);
                float p3 = fast_exp2(stv[s][3]);
                uint2 pr;
                pr.x = pack_rnd(p0, p1);
                pr.y = pack_rnd(p2, p3);
                *(uint2*)(PtW + (g * 16 + l16) * 72 + s * 16 + quad * 4) = pr;
            }
        }

#pragma unroll
        for (int ks = 0; ks < 2; ++ks) {
            short8 pf0 = *(const short8*)(PtW + ( 0 + l16) * 72 + ks * 32 + quad * 8);
            short8 pf1 = *(const short8*)(PtW + (16 + l16) * 72 + ks * 32 + quad * 8);
            short8 vh0 = *(const short8*)(Vsr + ( 0 + l16) * 72 + ks * 32 + quad * 8);
            short8 vh1 = *(const short8*)(Vsr + (16 + l16) * 72 + ks * 32 + quad * 8);
            o[0][0] = __builtin_amdgcn_mfma_f32_16x16x32_bf16(vh0, pf0, o[0][0], 0, 0, 0);
            o[0][1] = __builtin_amdgcn_mfma_f32_16x16x32_bf16(vh1, pf0, o[0][1], 0, 0, 0);
            o[1][0] = __builtin_amdgcn_mfma_f32_16x16x32_bf16(vh0, pf1, o[1][0], 0, 0, 0);
            o[1][1] = __builtin_amdgcn_mfma_f32_16x16x32_bf16(vh1, pf1, o[1][1], 0, 0, 0);
            lacc[0] = __builtin_amdgcn_mfma_f32_16x16x32_bf16(ones, pf0, lacc[0], 0, 0, 0);
            lacc[1] = __builtin_amdgcn_mfma_f32_16x16x32_bf16(ones, pf1, lacc[1], 0, 0, 0);
        }
        __syncthreads();
    }

    // ---- epilogue: cross-team combine, normalize, transpose, split ----
    float (*OfB)[132] = (float(*)[132])smem;                 // [32][132] team1 O^T
    float* Lb = (float*)(smem + 16896);                      // [128] team1 l
    float (*OfA)[132] = (float(*)[132])(smem + 17408);       // [32][132] final

    if (team == 1) {
#pragma unroll
        for (int g = 0; g < 2; ++g) {
            const int q = w4 * 32 + g * 16 + l16;
#pragma unroll
            for (int half = 0; half < 2; ++half)
#pragma unroll
                for (int r = 0; r < 4; ++r)
                    OfB[half * 16 + quad * 4 + r][q] = o[g][half][r];
            if (quad == 0) Lb[q] = lacc[g][0];
        }
    }
    __syncthreads();
    if (team == 0) {
#pragma unroll
        for (int g = 0; g < 2; ++g) {
            const int q = w4 * 32 + g * 16 + l16;
            const float inv = 1.0f / (lacc[g][0] + Lb[q]);
#pragma unroll
            for (int half = 0; half < 2; ++half)
#pragma unroll
                for (int r = 0; r < 4; ++r) {
                    const int d = half * 16 + quad * 4 + r;
                    OfA[d][q] = (o[g][half][r] + OfB[d][q]) * inv;
                }
        }
    }
    __syncthreads();
    {
        const int q = t >> 2, db = (t & 3) * 8;
        unsigned ph[4], pl[4];
#pragma unroll
        for (int i = 0; i < 4; ++i)
            split_pack(OfA[db + 2 * i][q], OfA[db + 2 * i + 1][q], ph[i], pl[i]);
        const size_t off = ((size_t)b * N + i0 + q) * 128 + h * 32 + db;
        *(uint4*)(Oth + off) = *(uint4*)ph;
        *(uint4*)(Otl + off) = *(uint4*)pl;
    }
}

// ---------------------------------------------------------------------------
// Output GEMM, split-bf16 MFMA, LDS-staged B, inline-converted W (preloaded),
// + bias.  Grid (64 n, 4 m, 4 b), 256 threads.
// ---------------------------------------------------------------------------
__global__ __launch_bounds__(256) void gemm2_fused(
    const float* __restrict__ wo,
    const unsigned short* __restrict__ Oth, const unsigned short* __restrict__ Otl,
    const float* __restrict__ bias, float* __restrict__ y)
{
    const int N = N_TOK;
    const int b = blockIdx.z;
    const int row0 = blockIdx.y * 64;
    const int col0 = blockIdx.x * 64;
    const int t = threadIdx.x;
    const int wave = t >> 6, lane = t & 63;
    const int l16 = lane & 15, quad = lane >> 4;
    const int msub0 = (wave & 1) * 32, nsub0 = (wave >> 1) * 32;

    __shared__ __align__(16) char smem[17408];
    unsigned short* BsH = (unsigned short*)smem;           // [64][40]
    unsigned short* BsL = (unsigned short*)(smem + 5120);  // [64][40]
    float (*LdsF)[68] = (float(*)[68])smem;                // epilogue reuse

    short8 ah[4][2], al[4][2];
#pragma unroll
    for (int kc = 0; kc < 4; ++kc)
#pragma unroll
        for (int r = 0; r < 2; ++r)
            cvt_frag(wo + (size_t)(row0 + msub0 + r * 16 + l16) * 128 +
                         kc * 32 + quad * 8,
                     ah[kc][r], al[kc][r]);

    const int srow = t >> 2, sk = (t & 3) * 8;
    const unsigned short* gH = Oth + ((size_t)b * N + col0 + srow) * 128 + sk;
    const unsigned short* gL = Otl + ((size_t)b * N + col0 + srow) * 128 + sk;

    floatx4 acc[2][2] = {};
#pragma unroll
    for (int kc = 0; kc < 4; ++kc) {
        short8 hreg = *(const short8*)(gH + kc * 32);
        short8 lreg = *(const short8*)(gL + kc * 32);
        __syncthreads();
        *(short8*)(BsH + srow * 40 + sk) = hreg;
        *(short8*)(BsL + srow * 40 + sk) = lreg;
        __syncthreads();
        short8 bh0 = *(const short8*)(BsH + (nsub0 + l16) * 40 + quad * 8);
        short8 bh1 = *(const short8*)(BsH + (nsub0 + 16 + l16) * 40 + quad * 8);
        short8 bl0 = *(const short8*)(BsL + (nsub0 + l16) * 40 + quad * 8);
        short8 bl1 = *(const short8*)(BsL + (nsub0 + 16 + l16) * 40 + quad * 8);
        acc[0][0] = __builtin_amdgcn_mfma_f32_16x16x32_bf16(ah[kc][0], bh0, acc[0][0], 0, 0, 0);
        acc[0][1] = __builtin_amdgcn_mfma_f32_16x16x32_bf16(ah[kc][0], bh1, acc[0][1], 0, 0, 0);
        acc[1][0] = __builtin_amdgcn_mfma_f32_16x16x32_bf16(ah[kc][1], bh0, acc[1][0], 0, 0, 0);
        acc[1][1] = __builtin_amdgcn_mfma_f32_16x16x32_bf16(ah[kc][1], bh1, acc[1][1], 0, 0, 0);
        acc[0][0] = __builtin_amdgcn_mfma_f32_16x16x32_bf16(ah[kc][0], bl0, acc[0][0], 0, 0, 0);
        acc[0][1] = __builtin_amdgcn_mfma_f32_16x16x32_bf16(ah[kc][0], bl1, acc[0][1], 0, 0, 0);
        acc[1][0] = __builtin_amdgcn_mfma_f32_16x16x32_bf16(ah[kc][1], bl0, acc[1][0], 0, 0, 0);
        acc[1][1] = __builtin_amdgcn_mfma_f32_16x16x32_bf16(ah[kc][1], bl1, acc[1][1], 0, 0, 0);
        acc[0][0] = __builtin_amdgcn_mfma_f32_16x16x32_bf16(al[kc][0], bh0, acc[0][0], 0, 0, 0);
        acc[0][1] = __builtin_amdgcn_mfma_f32_16x16x32_bf16(al[kc][0], bh1, acc[0][1], 0, 0, 0);
        acc[1][0] = __builtin_amdgcn_mfma_f32_16x16x32_bf16(al[kc][1], bh0, acc[1][0], 0, 0, 0);
        acc[1][1] = __builtin_amdgcn_mfma_f32_16x16x32_bf16(al[kc][1], bh1, acc[1][1], 0, 0, 0);
    }

    __syncthreads();
#pragma unroll
    for (int i = 0; i < 2; ++i)
#pragma unroll
        for (int j = 0; j < 2; ++j) {
            const int m = msub0 + i * 16 + quad * 4;
            const int n = nsub0 + j * 16 + l16;
#pragma unroll
            for (int r = 0; r < 4; ++r) LdsF[m + r][n] = acc[i][j][r];
        }
    __syncthreads();
    const int m = t >> 2, nb = (t & 3) * 16;
    const float bv = bias[row0 + m];
    float* dst = y + ((size_t)b * 256 + row0 + m) * N + col0 + nb;
#pragma unroll
    for (int g = 0; g < 4; ++g) {
        float4 o4;
        o4.x = LdsF[m][nb + g * 4 + 0] + bv;
        o4.y = LdsF[m][nb + g * 4 + 1] + bv;
        o4.z = LdsF[m][nb + g * 4 + 2] + bv;
        o4.w = LdsF[m][nb + g * 4 + 3] + bv;
        *(float4*)(dst + g * 4) = o4;
    }
}

extern "C" void kernel_launch(void* const* d_in, const int* in_sizes, int n_in,
                              void* d_out, int out_size, void* d_ws, size_t ws_size,
                              hipStream_t stream) {
    const float* x     = (const float*)d_in[0];
    const float* w_qkv = (const float*)d_in[1];
    const float* w_out = (const float*)d_in[2];
    const float* b_out = (const float*)d_in[3];
    float* y = (float*)d_out;

    // workspace 20 MiB: Qp, Kp, Vp, Oth, Otl (4 MiB each)
    char* base = (char*)d_ws;
    unsigned short* Qp  = (unsigned short*)base;
    unsigned short* Kp  = Qp + (size_t)16 * N_TOK * 32;
    unsigned short* Vp  = Kp + (size_t)16 * N_TOK * 32;
    unsigned short* Oth = Vp + (size_t)16 * N_TOK * 32;
    unsigned short* Otl = Oth + (size_t)BATCH * N_TOK * 128;

    gemm1_fused<<<dim3(64, 6, BATCH), dim3(256), 0, stream>>>(
        w_qkv, x, Qp, Kp, Vp);
    attn_fused<<<dim3(32, 16), dim3(512), 0, stream>>>(Qp, Kp, Vp, Oth, Otl);
    gemm2_fused<<<dim3(64, 4, BATCH), dim3(256), 0, stream>>>(
        w_out, Oth, Otl, b_out, y);
}